// Round 6
// baseline (769.889 us; speedup 1.0000x reference)
//
#include <hip/hip_runtime.h>
#include <hip/hip_bf16.h>

#define B_   4
#define S_   8192
#define D_   512
#define DFF_ 2048
#define K_TOP 1024

typedef unsigned short u16;
typedef __attribute__((ext_vector_type(8))) short bf16x8;
typedef __attribute__((ext_vector_type(4))) float floatx4;

// monotonic float -> uint key (order-preserving)
__device__ __forceinline__ unsigned f2key(float f){
    unsigned u = __float_as_uint(f);
    return (u & 0x80000000u) ? ~u : (u | 0x80000000u);
}
// fp32 -> bf16 round-to-nearest-even
__device__ __forceinline__ u16 f2b(float f){
    unsigned u = __float_as_uint(f);
    u = (u + 0x7FFFu + ((u >> 16) & 1u)) >> 16;
    return (u16)u;
}
// fast tanh-gelu via v_exp_f32
__device__ __forceinline__ float gelu_fast(float v){
    float u = 1.5957691216f * v + 0.0713548162726f * v * v * v;
    float e = __expf(u);
    return v - v / (e + 1.0f);
}
// async global->LDS, 16B per lane (wave-uniform base + lane*16)
__device__ __forceinline__ void gl_lds16(const void* gptr, void* lptr){
    auto g = (const __attribute__((address_space(1))) unsigned int*)((uintptr_t)gptr);
    auto l = (__attribute__((address_space(3))) unsigned int*)((uintptr_t)lptr);
    __builtin_amdgcn_global_load_lds(g, l, 16, 0, 0);
}

// ---- cross-block flag sync (XCD-L2-safe) ----------------------------------
__device__ __forceinline__ void role_release(int* flag, int tid){
    __threadfence();                 // each thread: write-back own stores
    __syncthreads();                 // all waves' fences done
    if (tid == 0)
        __hip_atomic_fetch_add(flag, 1, __ATOMIC_RELEASE, __HIP_MEMORY_SCOPE_AGENT);
}
__device__ __forceinline__ void role_acquire(const int* flag, int target, int tid){
    if (tid == 0){
        while (__hip_atomic_load(flag, __ATOMIC_ACQUIRE, __HIP_MEMORY_SCOPE_AGENT) < target)
            __builtin_amdgcn_s_sleep(2);
    }
    __syncthreads();
    __threadfence();                 // invalidate stale caches before data reads
}

// flags (ints): [0]=router_done [1]=kth_done [2..18)=cw1[16] [18..22)=cw2[4]
// [22..54)=gcnt[32] [54..86)=h1cnt[32]
#define F_RC    0
#define F_KTH   1
#define F_CW1   2
#define F_CW2   18
#define F_GCNT  22
#define F_H1    54

__global__ void init_flags(int* flags){ flags[threadIdx.x] = 0; }

// GEMM operand tiles: [tile][kstep128][128 rows][16 chunks of 16B] bf16,
// chunk c of row r at global slot (c ^ (r&15)). BK=64 staging fetches one
// K-half's 8 chunks with pre-swizzled global addresses; LDS dest is linear.

// ======================= role bodies =======================================

// router + copy-all x->out (ffn2 overwrites selected rows strictly later)
__device__ __forceinline__ void role_router(int bx, int tid,
    const float4* __restrict__ x, float4* __restrict__ out,
    const float4* __restrict__ Wr4, const float* __restrict__ br,
    float* __restrict__ w_all)
{
    const int wv = tid >> 6, lane = tid & 63;
    const int t0 = bx * 64 + wv * 16;
    const float brv = br[0];
    const float4 wr0 = Wr4[lane], wr1 = Wr4[lane + 64];
    #pragma unroll
    for (int g = 0; g < 4; g++){
        float a[4];
        #pragma unroll
        for (int tt = 0; tt < 4; tt++){
            const int t = t0 + g * 4 + tt;
            const float4* xt = x + (size_t)t * 128;
            float4* ot = out + (size_t)t * 128;
            float4 v0 = xt[lane], v1 = xt[lane + 64];
            ot[lane] = v0; ot[lane + 64] = v1;
            a[tt] = v0.x*wr0.x + v0.y*wr0.y + v0.z*wr0.z + v0.w*wr0.w
                  + v1.x*wr1.x + v1.y*wr1.y + v1.z*wr1.z + v1.w*wr1.w;
        }
        #pragma unroll
        for (int off = 32; off > 0; off >>= 1){
            #pragma unroll
            for (int tt = 0; tt < 4; tt++) a[tt] += __shfl_down(a[tt], off, 64);
        }
        if (lane == 0){
            #pragma unroll
            for (int tt = 0; tt < 4; tt++) w_all[t0 + g * 4 + tt] = a[tt] + brv;
        }
    }
}

// exact k-th largest per batch (256 threads) + ballot compaction
// (verified in round-3 mega kernel)
__device__ __forceinline__ void role_kth(char* shm, int b, int tid,
    const float4* __restrict__ w_all4, int* __restrict__ counts,
    int* __restrict__ idx)
{
    unsigned* keys = (unsigned*)shm;                           // 32 KB
    unsigned (*hist)[256] = (unsigned(*)[256])(shm + 32768);   // 4 KB
    unsigned* sprefix = (unsigned*)(shm + 36864);
    int* sremk = (int*)(shm + 36872);
    int* lbase = (int*)(shm + 36880);
    const int wv = tid >> 6, lane = tid & 63;
    const float4* row4 = w_all4 + (size_t)b * (S_ / 4);

    #pragma unroll
    for (int i = 0; i < 8; i++){
        int j = tid + i * 256;
        float4 v = row4[j];
        keys[4*j+0] = f2key(v.x); keys[4*j+1] = f2key(v.y);
        keys[4*j+2] = f2key(v.z); keys[4*j+3] = f2key(v.w);
    }
    if (tid == 0){ *sprefix = 0u; *sremk = K_TOP; *lbase = 0; }
    __syncthreads();

    for (int pass = 3; pass >= 0; pass--){
        const int shift = pass * 8;
        #pragma unroll
        for (int i = 0; i < 4; i++) ((unsigned*)hist)[tid + i * 256] = 0u;
        __syncthreads();
        const unsigned mask_hi = (pass == 3) ? 0u : (0xFFFFFFFFu << (shift + 8));
        const unsigned pfx = *sprefix;
        #pragma unroll 8
        for (int i = 0; i < 32; i++){
            unsigned key = keys[tid + i * 256];
            if ((key & mask_hi) == pfx)
                atomicAdd(&hist[wv][(key >> shift) & 255u], 1u);
        }
        __syncthreads();
        if (wv == 0){
            const unsigned remk = (unsigned)*sremk;
            unsigned c[4];
            #pragma unroll
            for (int q = 0; q < 4; q++)
                c[q] = hist[0][4*lane+q] + hist[1][4*lane+q]
                     + hist[2][4*lane+q] + hist[3][4*lane+q];
            unsigned t = c[0] + c[1] + c[2] + c[3];
            unsigned ss = t;
            #pragma unroll
            for (int off = 1; off < 64; off <<= 1){
                unsigned o = __shfl_down(ss, off, 64);
                ss += (lane + off < 64) ? o : 0u;
            }
            const unsigned sgt = ss - t;
            unsigned suf[4];
            suf[3] = c[3] + sgt; suf[2] = c[2] + suf[3];
            suf[1] = c[1] + suf[2]; suf[0] = c[0] + suf[1];
            #pragma unroll
            for (int q = 0; q < 4; q++){
                unsigned nx = suf[q] - c[q];
                if (suf[q] >= remk && nx < remk){
                    *sprefix = pfx | ((unsigned)(4 * lane + q) << shift);
                    *sremk = (int)(remk - nx);
                }
            }
        }
        __syncthreads();
    }

    const unsigned thr = *sprefix;
    #pragma unroll 8
    for (int i = 0; i < 32; i++){
        int li = tid + i * 256;
        bool sel = keys[li] > thr;
        unsigned long long m = __ballot(sel);
        int wtot = (int)__popcll(m);
        if (wtot){
            int woff = 0;
            if (lane == 0) woff = atomicAdd(lbase, wtot);
            woff = __shfl(woff, 0, 64);
            if (sel){
                int pos = woff + (int)__popcll(m & ((1ull << lane) - 1ull));
                idx[b * 1024 + pos] = b * S_ + li;
            }
        }
    }
    __syncthreads();
    if (tid == 0) counts[b] = *lbase;
}

__device__ __forceinline__ void role_gather(int g, int tid,
    const float* __restrict__ x, const int* __restrict__ idx,
    const int* __restrict__ counts, u16* __restrict__ XbT)
{
    const int mt = g >> 2, s = g & 3;
    const int cl = tid & 15, r16 = tid >> 4;
    u16* base = XbT + (size_t)(mt * 4 + s) * 16384;
    #pragma unroll
    for (int it = 0; it < 8; it++){
        int r = r16 + it * 16;
        int mg = mt * 128 + r;
        if ((mg & 1023) < counts[mg >> 10]){
            const float* xp = x + (size_t)idx[mg] * D_ + s * 128 + cl * 8;
            float4 v0 = *(const float4*)xp;
            float4 v1 = *(const float4*)(xp + 4);
            bf16x8 bv;
            bv[0]=(short)f2b(v0.x); bv[1]=(short)f2b(v0.y);
            bv[2]=(short)f2b(v0.z); bv[3]=(short)f2b(v0.w);
            bv[4]=(short)f2b(v1.x); bv[5]=(short)f2b(v1.y);
            bv[6]=(short)f2b(v1.z); bv[7]=(short)f2b(v1.w);
            *(bf16x8*)&base[r * 128 + ((cl ^ (r & 15)) << 3)] = bv;
        }
    }
}

__device__ __forceinline__ void role_conv(char* shm, int cv, int tid,
    const float* __restrict__ W1, const float* __restrict__ W2,
    u16* __restrict__ W1t, u16* __restrict__ W2t)
{
    const float* src; u16* dst; int R, C, ct, ks;
    if (cv < 64){ src = W1; dst = W1t; R = D_;   C = DFF_; ct = cv & 15;        ks = cv >> 4; }
    else        { src = W2; dst = W2t; R = DFF_; C = D_;   ct = (cv - 64) & 3;  ks = (cv - 64) >> 2; }
    u16 (*tile)[132] = (u16(*)[132])shm;
    #pragma unroll
    for (int it = 0; it < 64; it++){
        int lin = it * 256 + tid;
        int kk = lin >> 7, nn = lin & 127;
        tile[kk][nn] = f2b(src[(size_t)(ks * 128 + kk) * C + ct * 128 + nn]);
    }
    __syncthreads();
    u16* base = dst + (size_t)(ct * (R / 128) + ks) * 16384;
    const int r = tid >> 1, h = tid & 1;
    #pragma unroll
    for (int c = 0; c < 8; c++){
        int cl = h * 8 + c;
        bf16x8 bv;
        #pragma unroll
        for (int e = 0; e < 8; e++) bv[e] = (short)tile[cl * 8 + e][r];
        *(bf16x8*)&base[r * 128 + ((cl ^ (r & 15)) << 3)] = bv;
    }
}

// GEMM1 Ht = gelu(Xsel @ W1 + b1), 128x128, BK=64 dbuf, counted vmcnt.
// LDS (bytes): A dbuf [0,16K)+[16K,32K); B dbuf [32K,48K)+[48K,64K).
__device__ __forceinline__ void role_ffn1(char* shm, int mBlk, int nBlk, int tid,
    const u16* __restrict__ XbT, const u16* __restrict__ W1t,
    const int* __restrict__ counts, const float* __restrict__ bias1,
    u16* __restrict__ Ht)
{
    const int lane = tid & 63, w = tid >> 6;
    const int wr = (w >> 1) * 64, wc = (w & 1) * 64;
    const int fr = lane & 15, quad = lane >> 4;

    const char* Abase = (const char*)(XbT + (size_t)mBlk * 4 * 16384);
    const char* Bbase = (const char*)(W1t + (size_t)nBlk * 4 * 16384);
    char* Al0 = shm + tid * 16;
    char* Bl0 = shm + 32768 + tid * 16;
    const int rr0 = tid >> 3, pp = tid & 7;

    auto stage = [&](const char* gbase, char* lb, int hs){
        const char* s0 = gbase + (size_t)(hs >> 1) * 32768;
        const int h = hs & 1;
        #pragma unroll
        for (int i = 0; i < 4; i++){
            int r = rr0 + i * 32;
            int pg = pp | (((h ^ (r >> 3)) & 1) << 3);
            gl_lds16(s0 + r * 256 + pg * 16, lb + i * 4096);
        }
    };
    stage(Abase, Al0, 0);
    stage(Bbase, Bl0, 0);

    floatx4 acc[4][4] = {};
    for (int hs = 0; hs < 8; hs++){
        __builtin_amdgcn_s_barrier();            // WAR: prev-iter reads done
        if (hs + 1 < 8){
            stage(Abase, Al0 + ((hs + 1) & 1) * 16384, hs + 1);
            stage(Bbase, Bl0 + ((hs + 1) & 1) * 16384, hs + 1);
            asm volatile("s_waitcnt vmcnt(8)" ::: "memory");
        } else {
            asm volatile("s_waitcnt vmcnt(0)" ::: "memory");
        }
        __builtin_amdgcn_sched_barrier(0);
        __builtin_amdgcn_s_barrier();            // all waves' stage(hs) landed
        const u16* Ab = (const u16*)(shm + (hs & 1) * 16384);
        const u16* Bb = (const u16*)(shm + 32768 + (hs & 1) * 16384);
        __builtin_amdgcn_s_setprio(1);
        #pragma unroll
        for (int ks2 = 0; ks2 < 2; ks2++){
            bf16x8 af[4], bf[4];
            #pragma unroll
            for (int i = 0; i < 4; i++){
                int r = wr + i * 16 + fr;
                af[i] = *(const bf16x8*)&Ab[r * 64 + (((ks2 * 4 + quad) ^ (r & 7)) << 3)];
            }
            #pragma unroll
            for (int j = 0; j < 4; j++){
                int r = wc + j * 16 + fr;
                bf[j] = *(const bf16x8*)&Bb[r * 64 + (((ks2 * 4 + quad) ^ (r & 7)) << 3)];
            }
            #pragma unroll
            for (int i = 0; i < 4; i++)
                #pragma unroll
                for (int j = 0; j < 4; j++)
                    acc[i][j] = __builtin_amdgcn_mfma_f32_16x16x32_bf16(af[i], bf[j], acc[i][j], 0, 0, 0);
        }
        __builtin_amdgcn_s_setprio(0);
    }

    float bj[4];
    #pragma unroll
    for (int j = 0; j < 4; j++) bj[j] = bias1[nBlk * 128 + wc + j * 16 + fr];

    __syncthreads();
    u16* Cs = (u16*)shm;             // 32KB: [128 r][128 c] swizzled
    #pragma unroll
    for (int i = 0; i < 4; i++){
        #pragma unroll
        for (int rg = 0; rg < 4; rg++){
            int r = wr + i * 16 + quad * 4 + rg;
            #pragma unroll
            for (int j = 0; j < 4; j++){
                int col = wc + j * 16 + fr;
                float v = gelu_fast(acc[i][j][rg] + bj[j]);
                Cs[r * 128 + ((((col >> 3) ^ (r & 15)) << 3) | (col & 7))] = f2b(v);
            }
        }
    }
    __syncthreads();
    const int r = tid >> 1, h = tid & 1;
    int mg = mBlk * 128 + r;
    if ((mg & 1023) < counts[mg >> 10]){
        u16* dstp = Ht + (((size_t)(mBlk * 2 + (r >> 6)) * 16 + nBlk) * 64 + (r & 63)) * 128;
        #pragma unroll
        for (int p = 0; p < 8; p++){
            int pc = h * 8 + p;
            *(bf16x8*)&dstp[pc << 3] = *(const bf16x8*)&Cs[r * 128 + (pc << 3)];
        }
    }
}

// GEMM2 out = (H @ W2 + b2) * w, 64x128, BK=64 dbuf, counted vmcnt.
// LDS (bytes): A dbuf [0,8K)+[8K,16K); B dbuf [16K,32K)+[32K,48K).
__device__ __forceinline__ void role_ffn2(char* shm, int mBlk, int nBlk, int tid,
    const u16* __restrict__ Ht, const u16* __restrict__ W2t,
    const int* __restrict__ counts, const int* __restrict__ idx,
    const float* __restrict__ w_all, const float* __restrict__ bias2,
    float* __restrict__ out)
{
    const int lane = tid & 63, w = tid >> 6;
    const int wr = (w >> 1) * 32, wc = (w & 1) * 64;
    const int fr = lane & 15, quad = lane >> 4;

    const char* Abase = (const char*)(Ht + (size_t)mBlk * 16 * 8192);
    const char* Bbase = (const char*)(W2t + (size_t)nBlk * 16 * 16384);
    char* Al0 = shm + tid * 16;
    char* Bl0 = shm + 16384 + tid * 16;
    const int rr0 = tid >> 3, pp = tid & 7;

    auto stage = [&](int buf, int hs){
        const int h = hs & 1;
        {   // A: [64][64] = 8KB, 2 loads/thread
            const char* s0 = Abase + (size_t)(hs >> 1) * 16384;
            char* l = Al0 + buf * 8192;
            #pragma unroll
            for (int i = 0; i < 2; i++){
                int r = rr0 + i * 32;
                int pg = pp | (((h ^ (r >> 3)) & 1) << 3);
                gl_lds16(s0 + r * 256 + pg * 16, l + i * 4096);
            }
        }
        {   // B: [128][64] = 16KB, 4 loads/thread
            const char* s0 = Bbase + (size_t)(hs >> 1) * 32768;
            char* l = Bl0 + buf * 16384;
            #pragma unroll
            for (int i = 0; i < 4; i++){
                int r = rr0 + i * 32;
                int pg = pp | (((h ^ (r >> 3)) & 1) << 3);
                gl_lds16(s0 + r * 256 + pg * 16, l + i * 4096);
            }
        }
    };

    stage(0, 0);
    floatx4 acc[2][4] = {};
    for (int hs = 0; hs < 32; hs++){
        __builtin_amdgcn_s_barrier();            // WAR: prev-iter reads done
        if (hs + 1 < 32){
            stage((hs + 1) & 1, hs + 1);
            asm volatile("s_waitcnt vmcnt(6)" ::: "memory");
        } else {
            asm volatile("s_waitcnt vmcnt(0)" ::: "memory");
        }
        __builtin_amdgcn_sched_barrier(0);
        __builtin_amdgcn_s_barrier();            // all waves' stage(hs) landed
        const u16* Ab = (const u16*)(shm + (hs & 1) * 8192);
        const u16* Bb = (const u16*)(shm + 16384 + (hs & 1) * 16384);
        __builtin_amdgcn_s_setprio(1);
        #pragma unroll
        for (int ks2 = 0; ks2 < 2; ks2++){
            bf16x8 af[2], bf[4];
            #pragma unroll
            for (int i = 0; i < 2; i++){
                int r = wr + i * 16 + fr;
                af[i] = *(const bf16x8*)&Ab[r * 64 + (((ks2 * 4 + quad) ^ (r & 7)) << 3)];
            }
            #pragma unroll
            for (int j = 0; j < 4; j++){
                int r = wc + j * 16 + fr;
                bf[j] = *(const bf16x8*)&Bb[r * 64 + (((ks2 * 4 + quad) ^ (r & 7)) << 3)];
            }
            #pragma unroll
            for (int i = 0; i < 2; i++)
                #pragma unroll
                for (int j = 0; j < 4; j++)
                    acc[i][j] = __builtin_amdgcn_mfma_f32_16x16x32_bf16(af[i], bf[j], acc[i][j], 0, 0, 0);
        }
        __builtin_amdgcn_s_setprio(0);
    }

    float bj[4];
    #pragma unroll
    for (int j = 0; j < 4; j++) bj[j] = bias2[nBlk * 128 + wc + j * 16 + fr];

    __syncthreads();
    float* Cs = (float*)shm;         // 32KB: [64 r][128 c]
    #pragma unroll
    for (int i = 0; i < 2; i++){
        #pragma unroll
        for (int rg = 0; rg < 4; rg++){
            int r = wr + i * 16 + quad * 4 + rg;
            #pragma unroll
            for (int j = 0; j < 4; j++)
                Cs[r * 128 + wc + j * 16 + fr] = acc[i][j][rg] + bj[j];
        }
    }
    __syncthreads();
    const int r = tid >> 2, q = tid & 3;
    int mg = mBlk * 64 + r;
    if ((mg & 1023) < counts[mg >> 10]){
        int token = idx[mg];
        float wt = w_all[token];
        float* op = out + (size_t)token * D_ + nBlk * 128 + q * 32;
        const float4* cp = (const float4*)&Cs[r * 128 + q * 32];
        #pragma unroll
        for (int p = 0; p < 8; p++){
            float4 vv = cp[p];
            vv.x *= wt; vv.y *= wt; vv.z *= wt; vv.w *= wt;
            ((float4*)op)[p] = vv;
        }
    }
}

// ======================= persistent pipeline kernel ========================
// 512 blocks x 256 thr, 64 KB LDS -> exactly 2 blocks/CU, all co-resident
// (empirically proven by round-3 cooperative mega kernel at same shape).
__global__ __launch_bounds__(256, 2) void pipeline_kernel(
    const float* x, const float* Wr, const float* br,
    const float* W1, const float* b1, const float* W2, const float* b2,
    float* out, float* w_all, int* counts, int* idx,
    u16* XbT, u16* W1t, u16* W2t, u16* Ht, int* flags)
{
    __shared__ __align__(16) char shm[65536];
    const int bx = blockIdx.x, tid = threadIdx.x;

    // ---- stage 0: router + copy-all x->out (all 512 blocks) ----
    role_router(bx, tid, (const float4*)x, (float4*)out,
                (const float4*)Wr, br, w_all);
    role_release(&flags[F_RC], tid);

    // ---- stage 1: kth | gather | conv ----
    if (bx < 4){
        role_acquire(&flags[F_RC], 512, tid);
        role_kth(shm, bx, tid, (const float4*)w_all, counts, idx);
        role_release(&flags[F_KTH], tid);
    } else if (bx < 132){
        const int g = bx - 4;
        role_acquire(&flags[F_KTH], 4, tid);
        role_gather(g, tid, x, idx, counts, XbT);
        role_release(&flags[F_GCNT + (g >> 2)], tid);
    } else if (bx < 260){
        const int c = bx - 132;
        role_conv(shm, c, tid, W1, W2, W1t, W2t);
        if (c < 64) role_release(&flags[F_CW1 + (c & 15)], tid);
        else        role_release(&flags[F_CW2 + ((c - 64) & 3)], tid);
    }
    // blocks [260,512) fall through to stage 2 and wait on their deps

    // ---- stage 2: ffn1 (all 512 blocks, XCD-chunked tasks) ----
    {
        const int task = (bx & 7) * 64 + (bx >> 3);
        const int mBlk = task & 31, nBlk = task >> 5;
        role_acquire(&flags[F_CW1 + nBlk], 4, tid);
        role_acquire(&flags[F_GCNT + mBlk], 4, tid);
        role_ffn1(shm, mBlk, nBlk, tid, XbT, W1t, counts, b1, Ht);
        role_release(&flags[F_H1 + mBlk], tid);
    }

    // ---- stage 3: ffn2 (256 blocks) ----
    if (bx < 256){
        const int task = (bx & 7) * 32 + (bx >> 3);
        const int mBlk = task & 63, nBlk = task >> 6;
        role_acquire(&flags[F_CW2 + nBlk], 16, tid);
        role_acquire(&flags[F_H1 + (mBlk >> 1)], 16, tid);
        role_ffn2(shm, mBlk, nBlk, tid, Ht, W2t, counts, idx, w_all, b2, out);
    }
}

extern "C" void kernel_launch(void* const* d_in, const int* in_sizes, int n_in,
                              void* d_out, int out_size, void* d_ws, size_t ws_size,
                              hipStream_t stream)
{
    const float* x  = (const float*)d_in[0];
    const float* Wr = (const float*)d_in[2];
    const float* br = (const float*)d_in[3];
    const float* W1 = (const float*)d_in[4];
    const float* b1 = (const float*)d_in[5];
    const float* W2 = (const float*)d_in[6];
    const float* b2 = (const float*)d_in[7];
    float* out = (float*)d_out;
    char* ws = (char*)d_ws;

    // workspace layout (bytes)
    float* w_all  = (float*)(ws + 0);          // 128 KB
    int*   counts = (int*)  (ws + 131072);     // 16 B
    int*   idx    = (int*)  (ws + 131136);     // 16 KB [4][1024]
    int*   flags  = (int*)  (ws + 163840);     // 512 B
    u16*   XbT    = (u16*)  (ws + 720896);     // 4 MB  [32][4][128][128]
    u16*   W1t    = (u16*)  (ws + 4915200);    // 2 MB  [16][4][128][128]
    u16*   W2t    = (u16*)  (ws + 7012352);    // 2 MB  [4][16][128][128]
    u16*   Ht     = (u16*)  (ws + 9109504);    // 16 MB [64][16][64][128]

    init_flags<<<1, 128, 0, stream>>>(flags);
    pipeline_kernel<<<512, 256, 0, stream>>>(
        x, Wr, br, W1, b1, W2, b2, out,
        w_all, counts, idx, XbT, W1t, W2t, Ht, flags);
}

// Round 7
// 195.952 us; speedup vs baseline: 3.9290x; 3.9290x over previous
//
#include <hip/hip_runtime.h>
#include <hip/hip_bf16.h>

#define B_   4
#define S_   8192
#define D_   512
#define DFF_ 2048
#define K_TOP 1024

typedef unsigned short u16;
typedef __attribute__((ext_vector_type(8))) short bf16x8;
typedef __attribute__((ext_vector_type(4))) float floatx4;

// monotonic float -> uint key (order-preserving)
__device__ __forceinline__ unsigned f2key(float f){
    unsigned u = __float_as_uint(f);
    return (u & 0x80000000u) ? ~u : (u | 0x80000000u);
}
// fp32 -> bf16 round-to-nearest-even
__device__ __forceinline__ u16 f2b(float f){
    unsigned u = __float_as_uint(f);
    u = (u + 0x7FFFu + ((u >> 16) & 1u)) >> 16;
    return (u16)u;
}
// fast tanh-gelu via v_exp_f32
__device__ __forceinline__ float gelu_fast(float v){
    float u = 1.5957691216f * v + 0.0713548162726f * v * v * v;
    float e = __expf(u);
    return v - v / (e + 1.0f);
}
// async global->LDS, 16B per lane (wave-uniform base + lane*16)
__device__ __forceinline__ void gl_lds16(const void* gptr, void* lptr){
    auto g = (const __attribute__((address_space(1))) unsigned int*)((uintptr_t)gptr);
    auto l = (__attribute__((address_space(3))) unsigned int*)((uintptr_t)lptr);
    __builtin_amdgcn_global_load_lds(g, l, 16, 0, 0);
}

// GEMM B tiles: [tile][kstep128][128 rows][16 chunks of 16B] bf16,
// chunk c of row r at global slot (c ^ (r&15)). BK=64 staging fetches one
// K-half's 8 chunks with pre-swizzled global addresses; LDS dest is linear.

// ---------------- kernel 1: prep (router + ghist + weight conv) ------------
__global__ __launch_bounds__(256) void prep_kernel(
    const float* __restrict__ W1, const float* __restrict__ W2,
    u16* __restrict__ W1t, u16* __restrict__ W2t,
    const float4* __restrict__ x,
    const float4* __restrict__ Wr4, const float* __restrict__ br,
    float* __restrict__ w_all, unsigned* __restrict__ ghist)
{
    __shared__ __align__(16) unsigned char shmem[128 * 132 * 2]; // 33 KB union
    const int tid = threadIdx.x;
    const int bx = blockIdx.x;
    if (bx < 128){
        const float* src; u16* dst; int R, C, ct, ks;
        if (bx < 64){ src = W1; dst = W1t; R = D_;   C = DFF_; ct = bx & 15;        ks = bx >> 4; }
        else        { src = W2; dst = W2t; R = DFF_; C = D_;   ct = (bx - 64) & 3;  ks = (bx - 64) >> 2; }
        u16 (*tile)[132] = (u16(*)[132])shmem;
        #pragma unroll
        for (int it = 0; it < 64; it++){
            int lin = it * 256 + tid;
            int kk = lin >> 7, nn = lin & 127;
            tile[kk][nn] = f2b(src[(size_t)(ks * 128 + kk) * C + ct * 128 + nn]);
        }
        __syncthreads();
        u16* base = dst + (size_t)(ct * (R / 128) + ks) * 16384;
        const int r = tid >> 1, h = tid & 1;
        #pragma unroll
        for (int c = 0; c < 8; c++){
            int cl = h * 8 + c;
            bf16x8 bv;
            #pragma unroll
            for (int e = 0; e < 8; e++) bv[e] = (short)tile[cl * 8 + e][r];
            *(bf16x8*)&base[r * 128 + ((cl ^ (r & 15)) << 3)] = bv;
        }
    } else {
        unsigned* hist = (unsigned*)shmem;
        if (tid < 256) hist[tid] = 0u;
        __syncthreads();
        const int wb = bx - 128;                  // 0..511, 128 blocks/batch
        const int wv = tid >> 6, lane = tid & 63;
        const int t0 = wb * 64 + wv * 16;
        const float brv = br[0];
        const float4 wr0 = Wr4[lane], wr1 = Wr4[lane + 64];
        #pragma unroll
        for (int g = 0; g < 4; g++){
            float a[4];
            #pragma unroll
            for (int tt = 0; tt < 4; tt++){
                const float4* xt = x + (size_t)(t0 + g * 4 + tt) * 128;
                float4 v0 = xt[lane], v1 = xt[lane + 64];
                a[tt] = v0.x*wr0.x + v0.y*wr0.y + v0.z*wr0.z + v0.w*wr0.w
                      + v1.x*wr1.x + v1.y*wr1.y + v1.z*wr1.z + v1.w*wr1.w;
            }
            #pragma unroll
            for (int off = 32; off > 0; off >>= 1){
                #pragma unroll
                for (int tt = 0; tt < 4; tt++) a[tt] += __shfl_down(a[tt], off, 64);
            }
            if (lane == 0){
                #pragma unroll
                for (int tt = 0; tt < 4; tt++){
                    float wt = a[tt] + brv;
                    w_all[t0 + g * 4 + tt] = wt;
                    atomicAdd(&hist[f2key(wt) >> 24], 1u);
                }
            }
        }
        __syncthreads();
        if (tid < 256) ghist[wb * 256 + tid] = hist[tid];   // non-atomic row
    }
}

// ------- kernel 2: exact k-th largest per batch, wave0-scan radix ----------
__global__ __launch_bounds__(1024) void kth_compact_kernel(
    const float4* __restrict__ w_all4, const unsigned* __restrict__ ghist,
    int* __restrict__ counts, int* __restrict__ idx)
{
    __shared__ unsigned keys[S_];
    __shared__ unsigned hist[4][256];
    __shared__ unsigned sprefix;
    __shared__ int sremk;
    __shared__ int lbase;
    const int b = blockIdx.x, tid = threadIdx.x;
    const int wv = tid >> 6, lane = tid & 63;
    const float4* row4 = w_all4 + (size_t)b * (S_ / 4);

    #pragma unroll
    for (int i = 0; i < 2; i++){
        int j = tid + i * 1024;
        float4 v = row4[j];
        keys[4*j+0] = f2key(v.x); keys[4*j+1] = f2key(v.y);
        keys[4*j+2] = f2key(v.z); keys[4*j+3] = f2key(v.w);
    }
    // coarse top-byte hist: 4 row-groups of 32 prep-rows each -> hist[q][bin]
    {
        const int bin = tid & 255, q = tid >> 8;
        unsigned s = 0;
        const unsigned* gh = ghist + (size_t)(b * 128 + q * 32) * 256 + bin;
        #pragma unroll 8
        for (int j = 0; j < 32; j++) s += gh[j * 256];
        hist[q][bin] = s;
    }
    if (tid == 0){ sprefix = 0u; sremk = K_TOP; lbase = 0; }
    __syncthreads();

    for (int pass = 3; pass >= 0; pass--){
        const int shift = pass * 8;
        if (pass < 3){
            ((unsigned*)hist)[tid] = 0u;
            __syncthreads();
            const unsigned mask_hi = 0xFFFFFFFFu << (shift + 8);
            const unsigned pfx = sprefix;
            #pragma unroll
            for (int i = 0; i < 8; i++){
                unsigned key = keys[tid + i * 1024];
                if ((key & mask_hi) == pfx)
                    atomicAdd(&hist[wv & 3][(key >> shift) & 255u], 1u);
            }
            __syncthreads();
        }
        if (wv == 0){
            const unsigned remk = (unsigned)sremk;
            const unsigned pfx = sprefix;
            unsigned c[4];
            #pragma unroll
            for (int q = 0; q < 4; q++)
                c[q] = hist[0][4*lane+q] + hist[1][4*lane+q]
                     + hist[2][4*lane+q] + hist[3][4*lane+q];
            unsigned t = c[0] + c[1] + c[2] + c[3];
            unsigned ss = t;
            #pragma unroll
            for (int off = 1; off < 64; off <<= 1){
                unsigned o = __shfl_down(ss, off, 64);
                ss += (lane + off < 64) ? o : 0u;
            }
            const unsigned sgt = ss - t;
            unsigned suf[4];
            suf[3] = c[3] + sgt; suf[2] = c[2] + suf[3];
            suf[1] = c[1] + suf[2]; suf[0] = c[0] + suf[1];
            #pragma unroll
            for (int q = 0; q < 4; q++){
                unsigned nx = suf[q] - c[q];
                if (suf[q] >= remk && nx < remk){
                    sprefix = pfx | ((unsigned)(4 * lane + q) << shift);
                    sremk = (int)(remk - nx);
                }
            }
        }
        __syncthreads();
    }

    const unsigned thr = sprefix;
    #pragma unroll
    for (int i = 0; i < 8; i++){
        int li = tid + i * 1024;
        bool sel = keys[li] > thr;
        unsigned long long m = __ballot(sel);
        int wtot = (int)__popcll(m);
        if (wtot){
            int woff = 0;
            if (lane == 0) woff = atomicAdd(&lbase, wtot);
            woff = __shfl(woff, 0, 64);
            if (sel){
                int pos = woff + (int)__popcll(m & ((1ull << lane) - 1ull));
                idx[b * 1024 + pos] = b * S_ + li;
            }
        }
    }
    __syncthreads();
    if (tid == 0) counts[b] = lbase;
}

// --- kernel 3: GEMM1 Ht = gelu(Xsel @ W1 + b1), 128x128, BK=64 -------------
// A direct from fp32 x via idx: reg-stage 8 float4 -> f2b -> swizzled ds_write.
// LDS: A single buf [0,16K) + B dbuf [16K,32K)+[32K,48K) = 48KB -> 3 blk/CU.
// grid 768: 512 GEMM (XCD-grouped mBlk) + 256 copy-all blocks.
__global__ __launch_bounds__(256) void ffn1_kernel(
    const float* __restrict__ x, const int* __restrict__ idx,
    const u16* __restrict__ W1t, const int* __restrict__ counts,
    const float* __restrict__ bias1, u16* __restrict__ Ht,
    float4* __restrict__ out)
{
    __shared__ __align__(16) u16 smem[24576];     // 48 KB
    const int tid = threadIdx.x, bx = blockIdx.x;

    if (bx >= 512){                 // copy-all: 128 tokens/block
        const int wv = tid >> 6, lane = tid & 63;
        const int t0 = (bx - 512) * 128 + wv * 32;
        const float4* x4 = (const float4*)x;
        for (int tt = 0; tt < 32; tt++){
            const float4* xs = x4 + (size_t)(t0 + tt) * 128;
            float4* od = out + (size_t)(t0 + tt) * 128;
            od[lane]      = xs[lane];
            od[lane + 64] = xs[lane + 64];
        }
        return;
    }

    const int mBlk = (bx & 7) * 4 + ((bx >> 3) & 3);   // XCD keeps 4 mBlks
    const int nBlk = bx >> 5;
    const int lane = tid & 63, w = tid >> 6;
    const int wr = (w >> 1) * 64, wc = (w & 1) * 64;
    const int fr = lane & 15, quad = lane >> 4;

    // ---- A source setup (row per thread-pair) ----
    const int r = tid >> 1, h = tid & 1;
    const int mg = mBlk * 128 + r;
    const bool valid = (mg & 1023) < counts[mg >> 10];
    const int tok = valid ? idx[mg] : 0;
    const float* arow = x + (size_t)tok * 512 + h * 32;
    u16* Arow = smem + r * 64;                        // row base (elements)
    const int slotbase = h * 4;

    // ---- B staging (global_load_lds, pre-swizzled source) ----
    const char* Bbase = (const char*)(W1t + (size_t)nBlk * 4 * 16384);
    char* Bl0 = (char*)(smem + 8192) + tid * 16;      // byte 16384
    const int rr0 = tid >> 3, pp = tid & 7;
    auto stageB = [&](int buf, int hs){
        const char* s0 = Bbase + (size_t)(hs >> 1) * 32768;
        const int hh = hs & 1;
        char* lb = Bl0 + buf * 16384;
        #pragma unroll
        for (int i = 0; i < 4; i++){
            int rb = rr0 + i * 32;
            int pg = pp | (((hh ^ (rb >> 3)) & 1) << 3);
            gl_lds16(s0 + rb * 256 + pg * 16, lb + i * 4096);
        }
    };

    // prologue: A(0) regs + B(0)
    float4 ra[8];
    #pragma unroll
    for (int e = 0; e < 8; e++) ra[e] = ((const float4*)arow)[e];
    __builtin_amdgcn_sched_barrier(0);
    stageB(0, 0);

    floatx4 acc[4][4] = {};
    for (int hs = 0; hs < 8; hs++){
        __builtin_amdgcn_s_barrier();                 // prev compute done; A buf free
        asm volatile("s_waitcnt vmcnt(4)" ::: "memory");   // ra(hs) ready
        __builtin_amdgcn_sched_barrier(0);
        #pragma unroll
        for (int cc = 0; cc < 4; cc++){               // cvt + swizzled ds_write
            float4 v0 = ra[cc*2], v1 = ra[cc*2+1];
            bf16x8 bv;
            bv[0]=(short)f2b(v0.x); bv[1]=(short)f2b(v0.y);
            bv[2]=(short)f2b(v0.z); bv[3]=(short)f2b(v0.w);
            bv[4]=(short)f2b(v1.x); bv[5]=(short)f2b(v1.y);
            bv[6]=(short)f2b(v1.z); bv[7]=(short)f2b(v1.w);
            *(bf16x8*)&Arow[(((slotbase + cc) ^ (r & 7)) << 3)] = bv;
        }
        if (hs + 1 < 8){
            const float4* an = (const float4*)(arow + (hs + 1) * 64);
            #pragma unroll
            for (int e = 0; e < 8; e++) ra[e] = an[e];
            __builtin_amdgcn_sched_barrier(0);
            stageB((hs + 1) & 1, hs + 1);
            asm volatile("s_waitcnt vmcnt(12) lgkmcnt(0)" ::: "memory"); // B(hs)+A writes
        } else {
            asm volatile("s_waitcnt vmcnt(0) lgkmcnt(0)" ::: "memory");
        }
        __builtin_amdgcn_sched_barrier(0);
        __builtin_amdgcn_s_barrier();                 // all staging visible
        const u16* Ab = smem;                          // [128 r][64 k] swizzled
        const u16* Bb = (const u16*)((const char*)smem + 16384 + (hs & 1) * 16384);
        __builtin_amdgcn_s_setprio(1);
        #pragma unroll
        for (int ks2 = 0; ks2 < 2; ks2++){
            bf16x8 af[4], bf[4];
            #pragma unroll
            for (int i = 0; i < 4; i++){
                int rr = wr + i * 16 + fr;
                af[i] = *(const bf16x8*)&Ab[rr * 64 + (((ks2 * 4 + quad) ^ (rr & 7)) << 3)];
            }
            #pragma unroll
            for (int j = 0; j < 4; j++){
                int rr = wc + j * 16 + fr;
                bf[j] = *(const bf16x8*)&Bb[rr * 64 + (((ks2 * 4 + quad) ^ (rr & 7)) << 3)];
            }
            #pragma unroll
            for (int i = 0; i < 4; i++)
                #pragma unroll
                for (int j = 0; j < 4; j++)
                    acc[i][j] = __builtin_amdgcn_mfma_f32_16x16x32_bf16(af[i], bf[j], acc[i][j], 0, 0, 0);
        }
        __builtin_amdgcn_s_setprio(0);
    }

    float bj[4];
    #pragma unroll
    for (int j = 0; j < 4; j++) bj[j] = bias1[nBlk * 128 + wc + j * 16 + fr];

    __syncthreads();
    u16* Cs = smem;                  // 32KB: [128 r][128 c] swizzled
    #pragma unroll
    for (int i = 0; i < 4; i++){
        #pragma unroll
        for (int rg = 0; rg < 4; rg++){
            int rr = wr + i * 16 + quad * 4 + rg;
            #pragma unroll
            for (int j = 0; j < 4; j++){
                int col = wc + j * 16 + fr;
                float v = gelu_fast(acc[i][j][rg] + bj[j]);
                Cs[rr * 128 + ((((col >> 3) ^ (rr & 15)) << 3) | (col & 7))] = f2b(v);
            }
        }
    }
    __syncthreads();
    const int cr = tid >> 1, ch = tid & 1;
    int cmg = mBlk * 128 + cr;
    if ((cmg & 1023) < counts[cmg >> 10]){
        u16* dstp = Ht + (((size_t)(mBlk * 2 + (cr >> 6)) * 16 + nBlk) * 64 + (cr & 63)) * 128;
        #pragma unroll
        for (int p = 0; p < 8; p++){
            int pc = ch * 8 + p;
            *(bf16x8*)&dstp[pc << 3] = *(const bf16x8*)&Cs[cr * 128 + (pc << 3)];
        }
    }
}

// --- kernel 4: GEMM2 out = (H @ W2 + b2) * w, 64x128, BK=64 dbuf -----------
__global__ __launch_bounds__(256) void ffn2_kernel(
    const u16* __restrict__ Ht, const u16* __restrict__ W2t,
    const int* __restrict__ counts, const int* __restrict__ idx,
    const float* __restrict__ w_all, const float* __restrict__ bias2,
    float* __restrict__ out)
{
    __shared__ __align__(16) u16 smem[24576];     // A:2x8KB | B:2x16KB
    const int tid = threadIdx.x;
    const int bx = blockIdx.x;
    const int mBlk = bx & 63, nBlk = bx >> 6;
    const int lane = tid & 63, w = tid >> 6;
    const int wr = (w >> 1) * 32, wc = (w & 1) * 64;
    const int fr = lane & 15, quad = lane >> 4;

    const char* Abase = (const char*)(Ht + (size_t)mBlk * 16 * 8192);
    const char* Bbase = (const char*)(W2t + (size_t)nBlk * 16 * 16384);
    char* Al0 = (char*)smem + tid * 16;
    char* Bl0 = (char*)(smem + 8192) + tid * 16;
    const int rr0 = tid >> 3, pp = tid & 7;

    auto stage = [&](int buf, int hs){
        const int h = hs & 1;
        {   // A: [64][64] = 8KB, 2 loads
            const char* s0 = Abase + (size_t)(hs >> 1) * 16384;
            char* l = Al0 + buf * 8192;
            #pragma unroll
            for (int i = 0; i < 2; i++){
                int r = rr0 + i * 32;
                int pg = pp | (((h ^ (r >> 3)) & 1) << 3);
                gl_lds16(s0 + r * 256 + pg * 16, l + i * 4096);
            }
        }
        {   // B: [128][64] = 16KB, 4 loads
            const char* s0 = Bbase + (size_t)(hs >> 1) * 32768;
            char* l = Bl0 + buf * 16384;
            #pragma unroll
            for (int i = 0; i < 4; i++){
                int r = rr0 + i * 32;
                int pg = pp | (((h ^ (r >> 3)) & 1) << 3);
                gl_lds16(s0 + r * 256 + pg * 16, l + i * 4096);
            }
        }
    };

    stage(0, 0);
    floatx4 acc[2][4] = {};
    for (int hs = 0; hs < 32; hs++){
        __builtin_amdgcn_s_barrier();            // WAR: prev-iter reads done
        if (hs + 1 < 32){
            stage((hs + 1) & 1, hs + 1);
            asm volatile("s_waitcnt vmcnt(6)" ::: "memory");
        } else {
            asm volatile("s_waitcnt vmcnt(0)" ::: "memory");
        }
        __builtin_amdgcn_sched_barrier(0);
        __builtin_amdgcn_s_barrier();            // all waves' stage(hs) landed
        const u16* Ab = (const u16*)((const char*)smem + (hs & 1) * 8192);
        const u16* Bb = (const u16*)((const char*)smem + 16384 + (hs & 1) * 16384);
        __builtin_amdgcn_s_setprio(1);
        #pragma unroll
        for (int ks2 = 0; ks2 < 2; ks2++){
            bf16x8 af[2], bf[4];
            #pragma unroll
            for (int i = 0; i < 2; i++){
                int r = wr + i * 16 + fr;
                af[i] = *(const bf16x8*)&Ab[r * 64 + (((ks2 * 4 + quad) ^ (r & 7)) << 3)];
            }
            #pragma unroll
            for (int j = 0; j < 4; j++){
                int r = wc + j * 16 + fr;
                bf[j] = *(const bf16x8*)&Bb[r * 64 + (((ks2 * 4 + quad) ^ (r & 7)) << 3)];
            }
            #pragma unroll
            for (int i = 0; i < 2; i++)
                #pragma unroll
                for (int j = 0; j < 4; j++)
                    acc[i][j] = __builtin_amdgcn_mfma_f32_16x16x32_bf16(af[i], bf[j], acc[i][j], 0, 0, 0);
        }
        __builtin_amdgcn_s_setprio(0);
    }

    float bj[4];
    #pragma unroll
    for (int j = 0; j < 4; j++) bj[j] = bias2[nBlk * 128 + wc + j * 16 + fr];

    __syncthreads();
    float* Cs = (float*)smem;        // 32KB: [64 r][128 c]
    #pragma unroll
    for (int i = 0; i < 2; i++){
        #pragma unroll
        for (int rg = 0; rg < 4; rg++){
            int r = wr + i * 16 + quad * 4 + rg;
            #pragma unroll
            for (int j = 0; j < 4; j++)
                Cs[r * 128 + wc + j * 16 + fr] = acc[i][j][rg] + bj[j];
        }
    }
    __syncthreads();
    const int r = tid >> 2, q = tid & 3;
    int mg = mBlk * 64 + r;
    if ((mg & 1023) < counts[mg >> 10]){
        int token = idx[mg];
        float wt = w_all[token];
        float* op = out + (size_t)token * D_ + nBlk * 128 + q * 32;
        const float4* cp = (const float4*)&Cs[r * 128 + q * 32];
        #pragma unroll
        for (int p = 0; p < 8; p++){
            float4 vv = cp[p];
            vv.x *= wt; vv.y *= wt; vv.z *= wt; vv.w *= wt;
            ((float4*)op)[p] = vv;
        }
    }
}

extern "C" void kernel_launch(void* const* d_in, const int* in_sizes, int n_in,
                              void* d_out, int out_size, void* d_ws, size_t ws_size,
                              hipStream_t stream)
{
    const float* x  = (const float*)d_in[0];
    const float* Wr = (const float*)d_in[2];
    const float* br = (const float*)d_in[3];
    const float* W1 = (const float*)d_in[4];
    const float* b1 = (const float*)d_in[5];
    const float* W2 = (const float*)d_in[6];
    const float* b2 = (const float*)d_in[7];
    float* out = (float*)d_out;
    char* ws = (char*)d_ws;

    // workspace layout (bytes)
    float*    w_all  = (float*)   (ws + 0);         // 128 KB
    int*      counts = (int*)     (ws + 131072);    // 16 B
    int*      idx    = (int*)     (ws + 131136);    // 16 KB [4][1024]
    unsigned* ghist  = (unsigned*)(ws + 163840);    // 512 KB [512][256]
    u16*      W1t    = (u16*)     (ws + 4915200);   // 2 MB  [16][4][128][128]
    u16*      W2t    = (u16*)     (ws + 7012352);   // 2 MB  [4][16][128][128]
    u16*      Ht     = (u16*)     (ws + 9109504);   // 16 MB [64][16][64][128]

    prep_kernel<<<640, 256, 0, stream>>>(
        W1, W2, W1t, W2t, (const float4*)x,
        (const float4*)Wr, br, w_all, ghist);
    kth_compact_kernel<<<B_, 1024, 0, stream>>>(
        (const float4*)w_all, ghist, counts, idx);
    ffn1_kernel<<<768, 256, 0, stream>>>(
        x, idx, W1t, counts, b1, Ht, (float4*)out);
    ffn2_kernel<<<256, 256, 0, stream>>>(
        Ht, W2t, counts, idx, w_all, b2, out);
}

// Round 8
// 192.817 us; speedup vs baseline: 3.9928x; 1.0163x over previous
//
#include <hip/hip_runtime.h>
#include <hip/hip_bf16.h>

#define B_   4
#define S_   8192
#define D_   512
#define DFF_ 2048
#define K_TOP 1024

typedef unsigned short u16;
typedef __attribute__((ext_vector_type(8))) short bf16x8;
typedef __attribute__((ext_vector_type(4))) float floatx4;

// monotonic float -> uint key (order-preserving)
__device__ __forceinline__ unsigned f2key(float f){
    unsigned u = __float_as_uint(f);
    return (u & 0x80000000u) ? ~u : (u | 0x80000000u);
}
// fp32 -> bf16 round-to-nearest-even
__device__ __forceinline__ u16 f2b(float f){
    unsigned u = __float_as_uint(f);
    u = (u + 0x7FFFu + ((u >> 16) & 1u)) >> 16;
    return (u16)u;
}
// fast tanh-gelu via v_exp_f32
__device__ __forceinline__ float gelu_fast(float v){
    float u = 1.5957691216f * v + 0.0713548162726f * v * v * v;
    float e = __expf(u);
    return v - v / (e + 1.0f);
}
// async global->LDS, 16B per lane (wave-uniform base + lane*16)
__device__ __forceinline__ void gl_lds16(const void* gptr, void* lptr){
    auto g = (const __attribute__((address_space(1))) unsigned int*)((uintptr_t)gptr);
    auto l = (__attribute__((address_space(3))) unsigned int*)((uintptr_t)lptr);
    __builtin_amdgcn_global_load_lds(g, l, 16, 0, 0);
}

// GEMM B tiles: [tile][kstep128][128 rows][16 chunks of 16B] bf16,
// chunk c of row r at global slot (c ^ (r&15)). BK=64 staging fetches one
// K-half's 8 chunks with pre-swizzled global addresses; LDS dest is linear.

// ---------------- kernel 1: prep (router + copy-all + ghist + weight conv) -
// blocks [0,128): weight conversion. blocks [128,640): router + x->out copy.
__global__ __launch_bounds__(256) void prep_kernel(
    const float* __restrict__ W1, const float* __restrict__ W2,
    u16* __restrict__ W1t, u16* __restrict__ W2t,
    const float4* __restrict__ x, float4* __restrict__ out,
    const float4* __restrict__ Wr4, const float* __restrict__ br,
    float* __restrict__ w_all, unsigned* __restrict__ ghist)
{
    __shared__ __align__(16) unsigned char shmem[128 * 132 * 2]; // 33 KB union
    const int tid = threadIdx.x;
    const int bx = blockIdx.x;
    if (bx < 128){
        const float* src; u16* dst; int R, C, ct, ks;
        if (bx < 64){ src = W1; dst = W1t; R = D_;   C = DFF_; ct = bx & 15;        ks = bx >> 4; }
        else        { src = W2; dst = W2t; R = DFF_; C = D_;   ct = (bx - 64) & 3;  ks = (bx - 64) >> 2; }
        u16 (*tile)[132] = (u16(*)[132])shmem;
        #pragma unroll
        for (int it = 0; it < 64; it++){
            int lin = it * 256 + tid;
            int kk = lin >> 7, nn = lin & 127;
            tile[kk][nn] = f2b(src[(size_t)(ks * 128 + kk) * C + ct * 128 + nn]);
        }
        __syncthreads();
        u16* base = dst + (size_t)(ct * (R / 128) + ks) * 16384;
        const int r = tid >> 1, h = tid & 1;
        #pragma unroll
        for (int c = 0; c < 8; c++){
            int cl = h * 8 + c;
            bf16x8 bv;
            #pragma unroll
            for (int e = 0; e < 8; e++) bv[e] = (short)tile[cl * 8 + e][r];
            *(bf16x8*)&base[r * 128 + ((cl ^ (r & 15)) << 3)] = bv;
        }
    } else {
        unsigned* hist = (unsigned*)shmem;
        if (tid < 256) hist[tid] = 0u;
        __syncthreads();
        const int wb = bx - 128;                  // 0..511, 128 blocks/batch
        const int wv = tid >> 6, lane = tid & 63;
        const int t0 = wb * 64 + wv * 16;
        const float brv = br[0];
        const float4 wr0 = Wr4[lane], wr1 = Wr4[lane + 64];
        #pragma unroll
        for (int g = 0; g < 4; g++){
            float a[4];
            #pragma unroll
            for (int tt = 0; tt < 4; tt++){
                const int t = t0 + g * 4 + tt;
                const float4* xt = x + (size_t)t * 128;
                float4* ot = out + (size_t)t * 128;
                float4 v0 = xt[lane], v1 = xt[lane + 64];
                ot[lane] = v0; ot[lane + 64] = v1;    // copy-all x->out
                a[tt] = v0.x*wr0.x + v0.y*wr0.y + v0.z*wr0.z + v0.w*wr0.w
                      + v1.x*wr1.x + v1.y*wr1.y + v1.z*wr1.z + v1.w*wr1.w;
            }
            #pragma unroll
            for (int off = 32; off > 0; off >>= 1){
                #pragma unroll
                for (int tt = 0; tt < 4; tt++) a[tt] += __shfl_down(a[tt], off, 64);
            }
            if (lane == 0){
                #pragma unroll
                for (int tt = 0; tt < 4; tt++){
                    float wt = a[tt] + brv;
                    w_all[t0 + g * 4 + tt] = wt;
                    atomicAdd(&hist[f2key(wt) >> 24], 1u);
                }
            }
        }
        __syncthreads();
        if (tid < 256) ghist[wb * 256 + tid] = hist[tid];   // non-atomic row
    }
}

// ------- kernel 2: exact k-th largest per batch, wave0-scan radix ----------
__global__ __launch_bounds__(1024) void kth_compact_kernel(
    const float4* __restrict__ w_all4, const unsigned* __restrict__ ghist,
    int* __restrict__ counts, int* __restrict__ idx)
{
    __shared__ unsigned keys[S_];
    __shared__ unsigned hist[4][256];
    __shared__ unsigned sprefix;
    __shared__ int sremk;
    __shared__ int lbase;
    const int b = blockIdx.x, tid = threadIdx.x;
    const int wv = tid >> 6, lane = tid & 63;
    const float4* row4 = w_all4 + (size_t)b * (S_ / 4);

    #pragma unroll
    for (int i = 0; i < 2; i++){
        int j = tid + i * 1024;
        float4 v = row4[j];
        keys[4*j+0] = f2key(v.x); keys[4*j+1] = f2key(v.y);
        keys[4*j+2] = f2key(v.z); keys[4*j+3] = f2key(v.w);
    }
    // coarse top-byte hist: 4 row-groups of 32 prep-rows each -> hist[q][bin]
    {
        const int bin = tid & 255, q = tid >> 8;
        unsigned s = 0;
        const unsigned* gh = ghist + (size_t)(b * 128 + q * 32) * 256 + bin;
        #pragma unroll 8
        for (int j = 0; j < 32; j++) s += gh[j * 256];
        hist[q][bin] = s;
    }
    if (tid == 0){ sprefix = 0u; sremk = K_TOP; lbase = 0; }
    __syncthreads();

    for (int pass = 3; pass >= 0; pass--){
        const int shift = pass * 8;
        if (pass < 3){
            ((unsigned*)hist)[tid] = 0u;
            __syncthreads();
            const unsigned mask_hi = 0xFFFFFFFFu << (shift + 8);
            const unsigned pfx = sprefix;
            #pragma unroll
            for (int i = 0; i < 8; i++){
                unsigned key = keys[tid + i * 1024];
                if ((key & mask_hi) == pfx)
                    atomicAdd(&hist[wv & 3][(key >> shift) & 255u], 1u);
            }
            __syncthreads();
        }
        if (wv == 0){
            const unsigned remk = (unsigned)sremk;
            const unsigned pfx = sprefix;
            unsigned c[4];
            #pragma unroll
            for (int q = 0; q < 4; q++)
                c[q] = hist[0][4*lane+q] + hist[1][4*lane+q]
                     + hist[2][4*lane+q] + hist[3][4*lane+q];
            unsigned t = c[0] + c[1] + c[2] + c[3];
            unsigned ss = t;
            #pragma unroll
            for (int off = 1; off < 64; off <<= 1){
                unsigned o = __shfl_down(ss, off, 64);
                ss += (lane + off < 64) ? o : 0u;
            }
            const unsigned sgt = ss - t;
            unsigned suf[4];
            suf[3] = c[3] + sgt; suf[2] = c[2] + suf[3];
            suf[1] = c[1] + suf[2]; suf[0] = c[0] + suf[1];
            #pragma unroll
            for (int q = 0; q < 4; q++){
                unsigned nx = suf[q] - c[q];
                if (suf[q] >= remk && nx < remk){
                    sprefix = pfx | ((unsigned)(4 * lane + q) << shift);
                    sremk = (int)(remk - nx);
                }
            }
        }
        __syncthreads();
    }

    const unsigned thr = sprefix;
    #pragma unroll
    for (int i = 0; i < 8; i++){
        int li = tid + i * 1024;
        bool sel = keys[li] > thr;
        unsigned long long m = __ballot(sel);
        int wtot = (int)__popcll(m);
        if (wtot){
            int woff = 0;
            if (lane == 0) woff = atomicAdd(&lbase, wtot);
            woff = __shfl(woff, 0, 64);
            if (sel){
                int pos = woff + (int)__popcll(m & ((1ull << lane) - 1ull));
                idx[b * 1024 + pos] = b * S_ + li;
            }
        }
    }
    __syncthreads();
    if (tid == 0) counts[b] = lbase;
}

// --- kernel 3: GEMM1 Ht = gelu(Xsel @ W1 + b1), 128x128, BK=64 -------------
// A direct from fp32 x via idx: reg-stage 8 float4 -> f2b -> swizzled ds_write.
// LDS: A single buf [0,16K) + B dbuf [16K,32K)+[32K,48K) = 48KB -> 3 blk/CU.
// grid 512 (XCD-grouped mBlk), GEMM only.
__global__ __launch_bounds__(256) void ffn1_kernel(
    const float* __restrict__ x, const int* __restrict__ idx,
    const u16* __restrict__ W1t, const int* __restrict__ counts,
    const float* __restrict__ bias1, u16* __restrict__ Ht)
{
    __shared__ __align__(16) u16 smem[24576];     // 48 KB
    const int tid = threadIdx.x, bx = blockIdx.x;

    const int mBlk = (bx & 7) * 4 + ((bx >> 3) & 3);   // XCD keeps 4 mBlks
    const int nBlk = bx >> 5;
    const int lane = tid & 63, w = tid >> 6;
    const int wr = (w >> 1) * 64, wc = (w & 1) * 64;
    const int fr = lane & 15, quad = lane >> 4;

    // ---- A source setup (row per thread-pair) ----
    const int r = tid >> 1, h = tid & 1;
    const int mg = mBlk * 128 + r;
    const bool valid = (mg & 1023) < counts[mg >> 10];
    const int tok = valid ? idx[mg] : 0;
    const float* arow = x + (size_t)tok * 512 + h * 32;
    u16* Arow = smem + r * 64;                        // row base (elements)
    const int slotbase = h * 4;

    // ---- B staging (global_load_lds, pre-swizzled source) ----
    const char* Bbase = (const char*)(W1t + (size_t)nBlk * 4 * 16384);
    char* Bl0 = (char*)(smem + 8192) + tid * 16;      // byte 16384
    const int rr0 = tid >> 3, pp = tid & 7;
    auto stageB = [&](int buf, int hs){
        const char* s0 = Bbase + (size_t)(hs >> 1) * 32768;
        const int hh = hs & 1;
        char* lb = Bl0 + buf * 16384;
        #pragma unroll
        for (int i = 0; i < 4; i++){
            int rb = rr0 + i * 32;
            int pg = pp | (((hh ^ (rb >> 3)) & 1) << 3);
            gl_lds16(s0 + rb * 256 + pg * 16, lb + i * 4096);
        }
    };

    // prologue: A(0) regs + B(0)
    float4 ra[8];
    #pragma unroll
    for (int e = 0; e < 8; e++) ra[e] = ((const float4*)arow)[e];
    __builtin_amdgcn_sched_barrier(0);
    stageB(0, 0);

    floatx4 acc[4][4] = {};
    for (int hs = 0; hs < 8; hs++){
        __builtin_amdgcn_s_barrier();                 // prev compute done; A buf free
        asm volatile("s_waitcnt vmcnt(4)" ::: "memory");   // ra(hs) ready
        __builtin_amdgcn_sched_barrier(0);
        #pragma unroll
        for (int cc = 0; cc < 4; cc++){               // cvt + swizzled ds_write
            float4 v0 = ra[cc*2], v1 = ra[cc*2+1];
            bf16x8 bv;
            bv[0]=(short)f2b(v0.x); bv[1]=(short)f2b(v0.y);
            bv[2]=(short)f2b(v0.z); bv[3]=(short)f2b(v0.w);
            bv[4]=(short)f2b(v1.x); bv[5]=(short)f2b(v1.y);
            bv[6]=(short)f2b(v1.z); bv[7]=(short)f2b(v1.w);
            *(bf16x8*)&Arow[(((slotbase + cc) ^ (r & 7)) << 3)] = bv;
        }
        if (hs + 1 < 8){
            const float4* an = (const float4*)(arow + (hs + 1) * 64);
            #pragma unroll
            for (int e = 0; e < 8; e++) ra[e] = an[e];
            __builtin_amdgcn_sched_barrier(0);
            stageB((hs + 1) & 1, hs + 1);
            asm volatile("s_waitcnt vmcnt(12) lgkmcnt(0)" ::: "memory"); // B(hs)+A writes
        } else {
            asm volatile("s_waitcnt vmcnt(0) lgkmcnt(0)" ::: "memory");
        }
        __builtin_amdgcn_sched_barrier(0);
        __builtin_amdgcn_s_barrier();                 // all staging visible
        const u16* Ab = smem;                          // [128 r][64 k] swizzled
        const u16* Bb = (const u16*)((const char*)smem + 16384 + (hs & 1) * 16384);
        __builtin_amdgcn_s_setprio(1);
        #pragma unroll
        for (int ks2 = 0; ks2 < 2; ks2++){
            bf16x8 af[4], bf[4];
            #pragma unroll
            for (int i = 0; i < 4; i++){
                int rr = wr + i * 16 + fr;
                af[i] = *(const bf16x8*)&Ab[rr * 64 + (((ks2 * 4 + quad) ^ (rr & 7)) << 3)];
            }
            #pragma unroll
            for (int j = 0; j < 4; j++){
                int rr = wc + j * 16 + fr;
                bf[j] = *(const bf16x8*)&Bb[rr * 64 + (((ks2 * 4 + quad) ^ (rr & 7)) << 3)];
            }
            #pragma unroll
            for (int i = 0; i < 4; i++)
                #pragma unroll
                for (int j = 0; j < 4; j++)
                    acc[i][j] = __builtin_amdgcn_mfma_f32_16x16x32_bf16(af[i], bf[j], acc[i][j], 0, 0, 0);
        }
        __builtin_amdgcn_s_setprio(0);
    }

    float bj[4];
    #pragma unroll
    for (int j = 0; j < 4; j++) bj[j] = bias1[nBlk * 128 + wc + j * 16 + fr];

    __syncthreads();
    u16* Cs = smem;                  // 32KB: [128 r][128 c] swizzled
    #pragma unroll
    for (int i = 0; i < 4; i++){
        #pragma unroll
        for (int rg = 0; rg < 4; rg++){
            int rr = wr + i * 16 + quad * 4 + rg;
            #pragma unroll
            for (int j = 0; j < 4; j++){
                int col = wc + j * 16 + fr;
                float v = gelu_fast(acc[i][j][rg] + bj[j]);
                Cs[rr * 128 + ((((col >> 3) ^ (rr & 15)) << 3) | (col & 7))] = f2b(v);
            }
        }
    }
    __syncthreads();
    const int cr = tid >> 1, ch = tid & 1;
    int cmg = mBlk * 128 + cr;
    if ((cmg & 1023) < counts[cmg >> 10]){
        u16* dstp = Ht + (((size_t)(mBlk * 2 + (cr >> 6)) * 16 + nBlk) * 64 + (cr & 63)) * 128;
        #pragma unroll
        for (int p = 0; p < 8; p++){
            int pc = ch * 8 + p;
            *(bf16x8*)&dstp[pc << 3] = *(const bf16x8*)&Cs[cr * 128 + (pc << 3)];
        }
    }
}

// --- kernel 4: GEMM2 out = (H @ W2 + b2) * w, 64x128, BK=64 dbuf -----------
__global__ __launch_bounds__(256) void ffn2_kernel(
    const u16* __restrict__ Ht, const u16* __restrict__ W2t,
    const int* __restrict__ counts, const int* __restrict__ idx,
    const float* __restrict__ w_all, const float* __restrict__ bias2,
    float* __restrict__ out)
{
    __shared__ __align__(16) u16 smem[24576];     // A:2x8KB | B:2x16KB
    const int tid = threadIdx.x;
    const int bx = blockIdx.x;
    const int mBlk = bx & 63, nBlk = bx >> 6;
    const int lane = tid & 63, w = tid >> 6;
    const int wr = (w >> 1) * 32, wc = (w & 1) * 64;
    const int fr = lane & 15, quad = lane >> 4;

    const char* Abase = (const char*)(Ht + (size_t)mBlk * 16 * 8192);
    const char* Bbase = (const char*)(W2t + (size_t)nBlk * 16 * 16384);
    char* Al0 = (char*)smem + tid * 16;
    char* Bl0 = (char*)(smem + 8192) + tid * 16;
    const int rr0 = tid >> 3, pp = tid & 7;

    auto stage = [&](int buf, int hs){
        const int h = hs & 1;
        {   // A: [64][64] = 8KB, 2 loads
            const char* s0 = Abase + (size_t)(hs >> 1) * 16384;
            char* l = Al0 + buf * 8192;
            #pragma unroll
            for (int i = 0; i < 2; i++){
                int r = rr0 + i * 32;
                int pg = pp | (((h ^ (r >> 3)) & 1) << 3);
                gl_lds16(s0 + r * 256 + pg * 16, l + i * 4096);
            }
        }
        {   // B: [128][64] = 16KB, 4 loads
            const char* s0 = Bbase + (size_t)(hs >> 1) * 32768;
            char* l = Bl0 + buf * 16384;
            #pragma unroll
            for (int i = 0; i < 4; i++){
                int r = rr0 + i * 32;
                int pg = pp | (((h ^ (r >> 3)) & 1) << 3);
                gl_lds16(s0 + r * 256 + pg * 16, l + i * 4096);
            }
        }
    };

    stage(0, 0);
    floatx4 acc[2][4] = {};
    for (int hs = 0; hs < 32; hs++){
        __builtin_amdgcn_s_barrier();            // WAR: prev-iter reads done
        if (hs + 1 < 32){
            stage((hs + 1) & 1, hs + 1);
            asm volatile("s_waitcnt vmcnt(6)" ::: "memory");
        } else {
            asm volatile("s_waitcnt vmcnt(0)" ::: "memory");
        }
        __builtin_amdgcn_sched_barrier(0);
        __builtin_amdgcn_s_barrier();            // all waves' stage(hs) landed
        const u16* Ab = (const u16*)((const char*)smem + (hs & 1) * 8192);
        const u16* Bb = (const u16*)((const char*)smem + 16384 + (hs & 1) * 16384);
        __builtin_amdgcn_s_setprio(1);
        #pragma unroll
        for (int ks2 = 0; ks2 < 2; ks2++){
            bf16x8 af[2], bf[4];
            #pragma unroll
            for (int i = 0; i < 2; i++){
                int r = wr + i * 16 + fr;
                af[i] = *(const bf16x8*)&Ab[r * 64 + (((ks2 * 4 + quad) ^ (r & 7)) << 3)];
            }
            #pragma unroll
            for (int j = 0; j < 4; j++){
                int r = wc + j * 16 + fr;
                bf[j] = *(const bf16x8*)&Bb[r * 64 + (((ks2 * 4 + quad) ^ (r & 7)) << 3)];
            }
            #pragma unroll
            for (int i = 0; i < 2; i++)
                #pragma unroll
                for (int j = 0; j < 4; j++)
                    acc[i][j] = __builtin_amdgcn_mfma_f32_16x16x32_bf16(af[i], bf[j], acc[i][j], 0, 0, 0);
        }
        __builtin_amdgcn_s_setprio(0);
    }

    float bj[4];
    #pragma unroll
    for (int j = 0; j < 4; j++) bj[j] = bias2[nBlk * 128 + wc + j * 16 + fr];

    __syncthreads();
    float* Cs = (float*)smem;        // 32KB: [64 r][128 c]
    #pragma unroll
    for (int i = 0; i < 2; i++){
        #pragma unroll
        for (int rg = 0; rg < 4; rg++){
            int r = wr + i * 16 + quad * 4 + rg;
            #pragma unroll
            for (int j = 0; j < 4; j++)
                Cs[r * 128 + wc + j * 16 + fr] = acc[i][j][rg] + bj[j];
        }
    }
    __syncthreads();
    const int r = tid >> 2, q = tid & 3;
    int mg = mBlk * 64 + r;
    if ((mg & 1023) < counts[mg >> 10]){
        int token = idx[mg];
        float wt = w_all[token];
        float* op = out + (size_t)token * D_ + nBlk * 128 + q * 32;
        const float4* cp = (const float4*)&Cs[r * 128 + q * 32];
        #pragma unroll
        for (int p = 0; p < 8; p++){
            float4 vv = cp[p];
            vv.x *= wt; vv.y *= wt; vv.z *= wt; vv.w *= wt;
            ((float4*)op)[p] = vv;
        }
    }
}

extern "C" void kernel_launch(void* const* d_in, const int* in_sizes, int n_in,
                              void* d_out, int out_size, void* d_ws, size_t ws_size,
                              hipStream_t stream)
{
    const float* x  = (const float*)d_in[0];
    const float* Wr = (const float*)d_in[2];
    const float* br = (const float*)d_in[3];
    const float* W1 = (const float*)d_in[4];
    const float* b1 = (const float*)d_in[5];
    const float* W2 = (const float*)d_in[6];
    const float* b2 = (const float*)d_in[7];
    float* out = (float*)d_out;
    char* ws = (char*)d_ws;

    // workspace layout (bytes)
    float*    w_all  = (float*)   (ws + 0);         // 128 KB
    int*      counts = (int*)     (ws + 131072);    // 16 B
    int*      idx    = (int*)     (ws + 131136);    // 16 KB [4][1024]
    unsigned* ghist  = (unsigned*)(ws + 163840);    // 512 KB [512][256]
    u16*      W1t    = (u16*)     (ws + 4915200);   // 2 MB  [16][4][128][128]
    u16*      W2t    = (u16*)     (ws + 7012352);   // 2 MB  [4][16][128][128]
    u16*      Ht     = (u16*)     (ws + 9109504);   // 16 MB [64][16][64][128]

    prep_kernel<<<640, 256, 0, stream>>>(
        W1, W2, W1t, W2t, (const float4*)x, (float4*)out,
        (const float4*)Wr, br, w_all, ghist);
    kth_compact_kernel<<<B_, 1024, 0, stream>>>(
        (const float4*)w_all, ghist, counts, idx);
    ffn1_kernel<<<512, 256, 0, stream>>>(
        x, idx, W1t, counts, b1, Ht);
    ffn2_kernel<<<256, 256, 0, stream>>>(
        Ht, W2t, counts, idx, w_all, b2, out);
}

// Round 9
// 186.667 us; speedup vs baseline: 4.1244x; 1.0329x over previous
//
#include <hip/hip_runtime.h>
#include <hip/hip_bf16.h>

#define B_   4
#define S_   8192
#define D_   512
#define DFF_ 2048
#define K_TOP 1024

typedef unsigned short u16;
typedef __attribute__((ext_vector_type(8))) short bf16x8;
typedef __attribute__((ext_vector_type(4))) float floatx4;

// monotonic float -> uint key (order-preserving)
__device__ __forceinline__ unsigned f2key(float f){
    unsigned u = __float_as_uint(f);
    return (u & 0x80000000u) ? ~u : (u | 0x80000000u);
}
// fp32 -> bf16 round-to-nearest-even
__device__ __forceinline__ u16 f2b(float f){
    unsigned u = __float_as_uint(f);
    u = (u + 0x7FFFu + ((u >> 16) & 1u)) >> 16;
    return (u16)u;
}
// fast tanh-gelu via v_exp_f32
__device__ __forceinline__ float gelu_fast(float v){
    float u = 1.5957691216f * v + 0.0713548162726f * v * v * v;
    float e = __expf(u);
    return v - v / (e + 1.0f);
}
// async global->LDS, 16B per lane (wave-uniform base + lane*16)
__device__ __forceinline__ void gl_lds16(const void* gptr, void* lptr){
    auto g = (const __attribute__((address_space(1))) unsigned int*)((uintptr_t)gptr);
    auto l = (__attribute__((address_space(3))) unsigned int*)((uintptr_t)lptr);
    __builtin_amdgcn_global_load_lds(g, l, 16, 0, 0);
}

// GEMM operand tiles: [tile][kstep128][128 rows][16 chunks of 16B] bf16,
// chunk c of row r at global slot (c ^ (r&15)). BK=64 staging fetches one
// K-half's 8 chunks with pre-swizzled global addresses; LDS dest is linear.

// ---------------- kernel 1: prep (router + copy-all + ghist + weight conv) -
// blocks [0,128): weight conversion. blocks [128,640): router + x->out copy.
__global__ __launch_bounds__(256) void prep_kernel(
    const float* __restrict__ W1, const float* __restrict__ W2,
    u16* __restrict__ W1t, u16* __restrict__ W2t,
    const float4* __restrict__ x, float4* __restrict__ out,
    const float4* __restrict__ Wr4, const float* __restrict__ br,
    float* __restrict__ w_all, unsigned* __restrict__ ghist)
{
    __shared__ __align__(16) unsigned char shmem[128 * 132 * 2]; // 33 KB union
    const int tid = threadIdx.x;
    const int bx = blockIdx.x;
    if (bx < 128){
        const float* src; u16* dst; int R, C, ct, ks;
        if (bx < 64){ src = W1; dst = W1t; R = D_;   C = DFF_; ct = bx & 15;        ks = bx >> 4; }
        else        { src = W2; dst = W2t; R = DFF_; C = D_;   ct = (bx - 64) & 3;  ks = (bx - 64) >> 2; }
        u16 (*tile)[132] = (u16(*)[132])shmem;
        #pragma unroll
        for (int it = 0; it < 64; it++){
            int lin = it * 256 + tid;
            int kk = lin >> 7, nn = lin & 127;
            tile[kk][nn] = f2b(src[(size_t)(ks * 128 + kk) * C + ct * 128 + nn]);
        }
        __syncthreads();
        u16* base = dst + (size_t)(ct * (R / 128) + ks) * 16384;
        const int r = tid >> 1, h = tid & 1;
        #pragma unroll
        for (int c = 0; c < 8; c++){
            int cl = h * 8 + c;
            bf16x8 bv;
            #pragma unroll
            for (int e = 0; e < 8; e++) bv[e] = (short)tile[cl * 8 + e][r];
            *(bf16x8*)&base[r * 128 + ((cl ^ (r & 15)) << 3)] = bv;
        }
    } else {
        unsigned* hist = (unsigned*)shmem;
        if (tid < 256) hist[tid] = 0u;
        __syncthreads();
        const int wb = bx - 128;                  // 0..511, 128 blocks/batch
        const int wv = tid >> 6, lane = tid & 63;
        const int t0 = wb * 64 + wv * 16;
        const float brv = br[0];
        const float4 wr0 = Wr4[lane], wr1 = Wr4[lane + 64];
        #pragma unroll
        for (int g = 0; g < 4; g++){
            float a[4];
            #pragma unroll
            for (int tt = 0; tt < 4; tt++){
                const int t = t0 + g * 4 + tt;
                const float4* xt = x + (size_t)t * 128;
                float4* ot = out + (size_t)t * 128;
                float4 v0 = xt[lane], v1 = xt[lane + 64];
                ot[lane] = v0; ot[lane + 64] = v1;    // copy-all x->out
                a[tt] = v0.x*wr0.x + v0.y*wr0.y + v0.z*wr0.z + v0.w*wr0.w
                      + v1.x*wr1.x + v1.y*wr1.y + v1.z*wr1.z + v1.w*wr1.w;
            }
            #pragma unroll
            for (int off = 32; off > 0; off >>= 1){
                #pragma unroll
                for (int tt = 0; tt < 4; tt++) a[tt] += __shfl_down(a[tt], off, 64);
            }
            if (lane == 0){
                #pragma unroll
                for (int tt = 0; tt < 4; tt++){
                    float wt = a[tt] + brv;
                    w_all[t0 + g * 4 + tt] = wt;
                    atomicAdd(&hist[f2key(wt) >> 24], 1u);
                }
            }
        }
        __syncthreads();
        if (tid < 256) ghist[wb * 256 + tid] = hist[tid];   // non-atomic row
    }
}

// ------- kernel 2: exact k-th largest per batch, wave0-scan radix ----------
__global__ __launch_bounds__(1024) void kth_compact_kernel(
    const float4* __restrict__ w_all4, const unsigned* __restrict__ ghist,
    int* __restrict__ counts, int* __restrict__ idx)
{
    __shared__ unsigned keys[S_];
    __shared__ unsigned hist[4][256];
    __shared__ unsigned sprefix;
    __shared__ int sremk;
    __shared__ int lbase;
    const int b = blockIdx.x, tid = threadIdx.x;
    const int wv = tid >> 6, lane = tid & 63;
    const float4* row4 = w_all4 + (size_t)b * (S_ / 4);

    #pragma unroll
    for (int i = 0; i < 2; i++){
        int j = tid + i * 1024;
        float4 v = row4[j];
        keys[4*j+0] = f2key(v.x); keys[4*j+1] = f2key(v.y);
        keys[4*j+2] = f2key(v.z); keys[4*j+3] = f2key(v.w);
    }
    // coarse top-byte hist: 4 row-groups of 32 prep-rows each -> hist[q][bin]
    {
        const int bin = tid & 255, q = tid >> 8;
        unsigned s = 0;
        const unsigned* gh = ghist + (size_t)(b * 128 + q * 32) * 256 + bin;
        #pragma unroll 8
        for (int j = 0; j < 32; j++) s += gh[j * 256];
        hist[q][bin] = s;
    }
    if (tid == 0){ sprefix = 0u; sremk = K_TOP; lbase = 0; }
    __syncthreads();

    for (int pass = 3; pass >= 0; pass--){
        const int shift = pass * 8;
        if (pass < 3){
            ((unsigned*)hist)[tid] = 0u;
            __syncthreads();
            const unsigned mask_hi = 0xFFFFFFFFu << (shift + 8);
            const unsigned pfx = sprefix;
            #pragma unroll
            for (int i = 0; i < 8; i++){
                unsigned key = keys[tid + i * 1024];
                if ((key & mask_hi) == pfx)
                    atomicAdd(&hist[wv & 3][(key >> shift) & 255u], 1u);
            }
            __syncthreads();
        }
        if (wv == 0){
            const unsigned remk = (unsigned)sremk;
            const unsigned pfx = sprefix;
            unsigned c[4];
            #pragma unroll
            for (int q = 0; q < 4; q++)
                c[q] = hist[0][4*lane+q] + hist[1][4*lane+q]
                     + hist[2][4*lane+q] + hist[3][4*lane+q];
            unsigned t = c[0] + c[1] + c[2] + c[3];
            unsigned ss = t;
            #pragma unroll
            for (int off = 1; off < 64; off <<= 1){
                unsigned o = __shfl_down(ss, off, 64);
                ss += (lane + off < 64) ? o : 0u;
            }
            const unsigned sgt = ss - t;
            unsigned suf[4];
            suf[3] = c[3] + sgt; suf[2] = c[2] + suf[3];
            suf[1] = c[1] + suf[2]; suf[0] = c[0] + suf[1];
            #pragma unroll
            for (int q = 0; q < 4; q++){
                unsigned nx = suf[q] - c[q];
                if (suf[q] >= remk && nx < remk){
                    sprefix = pfx | ((unsigned)(4 * lane + q) << shift);
                    sremk = (int)(remk - nx);
                }
            }
        }
        __syncthreads();
    }

    const unsigned thr = sprefix;
    #pragma unroll
    for (int i = 0; i < 8; i++){
        int li = tid + i * 1024;
        bool sel = keys[li] > thr;
        unsigned long long m = __ballot(sel);
        int wtot = (int)__popcll(m);
        if (wtot){
            int woff = 0;
            if (lane == 0) woff = atomicAdd(&lbase, wtot);
            woff = __shfl(woff, 0, 64);
            if (sel){
                int pos = woff + (int)__popcll(m & ((1ull << lane) - 1ull));
                idx[b * 1024 + pos] = b * S_ + li;
            }
        }
    }
    __syncthreads();
    if (tid == 0) counts[b] = lbase;
}

// --- kernel 3: gather selected x rows -> bf16 tiled+swizzled ---------------
// XbT tiles [32 mt][4 ks][128 r][128 k]; grid (32, 4). Pays the scatter ONCE.
__global__ __launch_bounds__(256) void gather_kernel(
    const float* __restrict__ x, const int* __restrict__ idx,
    const int* __restrict__ counts, u16* __restrict__ XbT)
{
    const int mt = blockIdx.x, s = blockIdx.y;
    const int cl = threadIdx.x & 15, r16 = threadIdx.x >> 4;
    u16* base = XbT + (size_t)(mt * 4 + s) * 16384;
    #pragma unroll
    for (int it = 0; it < 8; it++){
        int r = r16 + it * 16;
        int mg = mt * 128 + r;
        if ((mg & 1023) < counts[mg >> 10]){
            const float* xp = x + (size_t)idx[mg] * D_ + s * 128 + cl * 8;
            float4 v0 = *(const float4*)xp;
            float4 v1 = *(const float4*)(xp + 4);
            bf16x8 bv;
            bv[0]=(short)f2b(v0.x); bv[1]=(short)f2b(v0.y);
            bv[2]=(short)f2b(v0.z); bv[3]=(short)f2b(v0.w);
            bv[4]=(short)f2b(v1.x); bv[5]=(short)f2b(v1.y);
            bv[6]=(short)f2b(v1.z); bv[7]=(short)f2b(v1.w);
            *(bf16x8*)&base[r * 128 + ((cl ^ (r & 15)) << 3)] = bv;
        }
    }
}

// --- kernel 4: GEMM1 Ht = gelu(Xsel @ W1 + b1), 128x128, BK=64 dbuf --------
// A from XbT via global_load_lds (coalesced). LDS 64 KB -> 2 blk/CU.
// grid 512, XCD-grouped mBlk so each XCD's L2 holds 4 A-panels.
__global__ __launch_bounds__(256) void ffn1_kernel(
    const u16* __restrict__ XbT, const u16* __restrict__ W1t,
    const int* __restrict__ counts, const float* __restrict__ bias1,
    u16* __restrict__ Ht)
{
    __shared__ __align__(16) u16 smem[32768];     // A:2x16KB | B:2x16KB = 64 KB
    const int tid = threadIdx.x, bx = blockIdx.x;
    const int mBlk = (bx & 7) * 4 + ((bx >> 3) & 3);   // XCD keeps 4 mBlks
    const int nBlk = bx >> 5;
    const int lane = tid & 63, w = tid >> 6;
    const int wr = (w >> 1) * 64, wc = (w & 1) * 64;
    const int fr = lane & 15, quad = lane >> 4;

    const char* Abase = (const char*)(XbT + (size_t)mBlk * 4 * 16384);
    const char* Bbase = (const char*)(W1t + (size_t)nBlk * 4 * 16384);
    char* Al0 = (char*)smem + tid * 16;
    char* Bl0 = (char*)(smem + 16384) + tid * 16;
    const int rr0 = tid >> 3, pp = tid & 7;

    auto stage = [&](const char* gbase, char* lb, int hs){
        const char* s0 = gbase + (size_t)(hs >> 1) * 32768;
        const int h = hs & 1;
        #pragma unroll
        for (int i = 0; i < 4; i++){
            int r = rr0 + i * 32;
            int pg = pp | (((h ^ (r >> 3)) & 1) << 3);
            gl_lds16(s0 + r * 256 + pg * 16, lb + i * 4096);
        }
    };

    stage(Abase, Al0, 0);
    stage(Bbase, Bl0, 0);

    floatx4 acc[4][4] = {};
    for (int hs = 0; hs < 8; hs++){
        __builtin_amdgcn_s_barrier();            // WAR: prev-iter reads done
        if (hs + 1 < 8){
            stage(Abase, Al0 + ((hs + 1) & 1) * 16384, hs + 1);
            stage(Bbase, Bl0 + ((hs + 1) & 1) * 16384, hs + 1);
            asm volatile("s_waitcnt vmcnt(8)" ::: "memory");
        } else {
            asm volatile("s_waitcnt vmcnt(0)" ::: "memory");
        }
        __builtin_amdgcn_sched_barrier(0);
        __builtin_amdgcn_s_barrier();            // all waves' stage(hs) landed
        const u16* Ab = smem + (hs & 1) * 8192;
        const u16* Bb = smem + 16384 + (hs & 1) * 8192;
        __builtin_amdgcn_s_setprio(1);
        #pragma unroll
        for (int ks2 = 0; ks2 < 2; ks2++){
            bf16x8 af[4], bf[4];
            #pragma unroll
            for (int i = 0; i < 4; i++){
                int r = wr + i * 16 + fr;
                af[i] = *(const bf16x8*)&Ab[r * 64 + (((ks2 * 4 + quad) ^ (r & 7)) << 3)];
            }
            #pragma unroll
            for (int j = 0; j < 4; j++){
                int r = wc + j * 16 + fr;
                bf[j] = *(const bf16x8*)&Bb[r * 64 + (((ks2 * 4 + quad) ^ (r & 7)) << 3)];
            }
            #pragma unroll
            for (int i = 0; i < 4; i++)
                #pragma unroll
                for (int j = 0; j < 4; j++)
                    acc[i][j] = __builtin_amdgcn_mfma_f32_16x16x32_bf16(af[i], bf[j], acc[i][j], 0, 0, 0);
        }
        __builtin_amdgcn_s_setprio(0);
    }

    float bj[4];
    #pragma unroll
    for (int j = 0; j < 4; j++) bj[j] = bias1[nBlk * 128 + wc + j * 16 + fr];

    __syncthreads();
    u16* Cs = smem;                  // 32KB: [128 r][128 c] swizzled
    #pragma unroll
    for (int i = 0; i < 4; i++){
        #pragma unroll
        for (int rg = 0; rg < 4; rg++){
            int r = wr + i * 16 + quad * 4 + rg;
            #pragma unroll
            for (int j = 0; j < 4; j++){
                int col = wc + j * 16 + fr;
                float v = gelu_fast(acc[i][j][rg] + bj[j]);
                Cs[r * 128 + ((((col >> 3) ^ (r & 15)) << 3) | (col & 7))] = f2b(v);
            }
        }
    }
    __syncthreads();
    const int r = tid >> 1, h = tid & 1;
    int mg = mBlk * 128 + r;
    if ((mg & 1023) < counts[mg >> 10]){
        u16* dstp = Ht + (((size_t)(mBlk * 2 + (r >> 6)) * 16 + nBlk) * 64 + (r & 63)) * 128;
        #pragma unroll
        for (int p = 0; p < 8; p++){
            int pc = h * 8 + p;
            *(bf16x8*)&dstp[pc << 3] = *(const bf16x8*)&Cs[r * 128 + (pc << 3)];
        }
    }
}

// --- kernel 5: GEMM2 out = (H @ W2 + b2) * w, 64x128, BK=64 dbuf -----------
__global__ __launch_bounds__(256) void ffn2_kernel(
    const u16* __restrict__ Ht, const u16* __restrict__ W2t,
    const int* __restrict__ counts, const int* __restrict__ idx,
    const float* __restrict__ w_all, const float* __restrict__ bias2,
    float* __restrict__ out)
{
    __shared__ __align__(16) u16 smem[24576];     // A:2x8KB | B:2x16KB
    const int tid = threadIdx.x;
    const int bx = blockIdx.x;
    const int mBlk = bx & 63, nBlk = bx >> 6;
    const int lane = tid & 63, w = tid >> 6;
    const int wr = (w >> 1) * 32, wc = (w & 1) * 64;
    const int fr = lane & 15, quad = lane >> 4;

    const char* Abase = (const char*)(Ht + (size_t)mBlk * 16 * 8192);
    const char* Bbase = (const char*)(W2t + (size_t)nBlk * 16 * 16384);
    char* Al0 = (char*)smem + tid * 16;
    char* Bl0 = (char*)(smem + 8192) + tid * 16;
    const int rr0 = tid >> 3, pp = tid & 7;

    auto stage = [&](int buf, int hs){
        const int h = hs & 1;
        {   // A: [64][64] = 8KB, 2 loads
            const char* s0 = Abase + (size_t)(hs >> 1) * 16384;
            char* l = Al0 + buf * 8192;
            #pragma unroll
            for (int i = 0; i < 2; i++){
                int r = rr0 + i * 32;
                int pg = pp | (((h ^ (r >> 3)) & 1) << 3);
                gl_lds16(s0 + r * 256 + pg * 16, l + i * 4096);
            }
        }
        {   // B: [128][64] = 16KB, 4 loads
            const char* s0 = Bbase + (size_t)(hs >> 1) * 32768;
            char* l = Bl0 + buf * 16384;
            #pragma unroll
            for (int i = 0; i < 4; i++){
                int r = rr0 + i * 32;
                int pg = pp | (((h ^ (r >> 3)) & 1) << 3);
                gl_lds16(s0 + r * 256 + pg * 16, l + i * 4096);
            }
        }
    };

    stage(0, 0);
    floatx4 acc[2][4] = {};
    for (int hs = 0; hs < 32; hs++){
        __builtin_amdgcn_s_barrier();            // WAR: prev-iter reads done
        if (hs + 1 < 32){
            stage((hs + 1) & 1, hs + 1);
            asm volatile("s_waitcnt vmcnt(6)" ::: "memory");
        } else {
            asm volatile("s_waitcnt vmcnt(0)" ::: "memory");
        }
        __builtin_amdgcn_sched_barrier(0);
        __builtin_amdgcn_s_barrier();            // all waves' stage(hs) landed
        const u16* Ab = (const u16*)((const char*)smem + (hs & 1) * 8192);
        const u16* Bb = (const u16*)((const char*)smem + 16384 + (hs & 1) * 16384);
        __builtin_amdgcn_s_setprio(1);
        #pragma unroll
        for (int ks2 = 0; ks2 < 2; ks2++){
            bf16x8 af[2], bf[4];
            #pragma unroll
            for (int i = 0; i < 2; i++){
                int r = wr + i * 16 + fr;
                af[i] = *(const bf16x8*)&Ab[r * 64 + (((ks2 * 4 + quad) ^ (r & 7)) << 3)];
            }
            #pragma unroll
            for (int j = 0; j < 4; j++){
                int r = wc + j * 16 + fr;
                bf[j] = *(const bf16x8*)&Bb[r * 64 + (((ks2 * 4 + quad) ^ (r & 7)) << 3)];
            }
            #pragma unroll
            for (int i = 0; i < 2; i++)
                #pragma unroll
                for (int j = 0; j < 4; j++)
                    acc[i][j] = __builtin_amdgcn_mfma_f32_16x16x32_bf16(af[i], bf[j], acc[i][j], 0, 0, 0);
        }
        __builtin_amdgcn_s_setprio(0);
    }

    float bj[4];
    #pragma unroll
    for (int j = 0; j < 4; j++) bj[j] = bias2[nBlk * 128 + wc + j * 16 + fr];

    __syncthreads();
    float* Cs = (float*)smem;        // 32KB: [64 r][128 c]
    #pragma unroll
    for (int i = 0; i < 2; i++){
        #pragma unroll
        for (int rg = 0; rg < 4; rg++){
            int r = wr + i * 16 + quad * 4 + rg;
            #pragma unroll
            for (int j = 0; j < 4; j++)
                Cs[r * 128 + wc + j * 16 + fr] = acc[i][j][rg] + bj[j];
        }
    }
    __syncthreads();
    const int r = tid >> 2, q = tid & 3;
    int mg = mBlk * 64 + r;
    if ((mg & 1023) < counts[mg >> 10]){
        int token = idx[mg];
        float wt = w_all[token];
        float* op = out + (size_t)token * D_ + nBlk * 128 + q * 32;
        const float4* cp = (const float4*)&Cs[r * 128 + q * 32];
        #pragma unroll
        for (int p = 0; p < 8; p++){
            float4 vv = cp[p];
            vv.x *= wt; vv.y *= wt; vv.z *= wt; vv.w *= wt;
            ((float4*)op)[p] = vv;
        }
    }
}

extern "C" void kernel_launch(void* const* d_in, const int* in_sizes, int n_in,
                              void* d_out, int out_size, void* d_ws, size_t ws_size,
                              hipStream_t stream)
{
    const float* x  = (const float*)d_in[0];
    const float* Wr = (const float*)d_in[2];
    const float* br = (const float*)d_in[3];
    const float* W1 = (const float*)d_in[4];
    const float* b1 = (const float*)d_in[5];
    const float* W2 = (const float*)d_in[6];
    const float* b2 = (const float*)d_in[7];
    float* out = (float*)d_out;
    char* ws = (char*)d_ws;

    // workspace layout (bytes)
    float*    w_all  = (float*)   (ws + 0);         // 128 KB
    int*      counts = (int*)     (ws + 131072);    // 16 B
    int*      idx    = (int*)     (ws + 131136);    // 16 KB [4][1024]
    unsigned* ghist  = (unsigned*)(ws + 163840);    // 512 KB [512][256]
    u16*      XbT    = (u16*)     (ws + 720896);    // 4 MB  [32][4][128][128]
    u16*      W1t    = (u16*)     (ws + 4915200);   // 2 MB  [16][4][128][128]
    u16*      W2t    = (u16*)     (ws + 7012352);   // 2 MB  [4][16][128][128]
    u16*      Ht     = (u16*)     (ws + 9109504);   // 16 MB [64][16][64][128]

    prep_kernel<<<640, 256, 0, stream>>>(
        W1, W2, W1t, W2t, (const float4*)x, (float4*)out,
        (const float4*)Wr, br, w_all, ghist);
    kth_compact_kernel<<<B_, 1024, 0, stream>>>(
        (const float4*)w_all, ghist, counts, idx);
    gather_kernel<<<dim3(32, 4), 256, 0, stream>>>(x, idx, counts, XbT);
    ffn1_kernel<<<512, 256, 0, stream>>>(
        XbT, W1t, counts, b1, Ht);
    ffn2_kernel<<<256, 256, 0, stream>>>(
        Ht, W2t, counts, idx, w_all, b2, out);
}

// Round 10
// 186.161 us; speedup vs baseline: 4.1356x; 1.0027x over previous
//
#include <hip/hip_runtime.h>
#include <hip/hip_bf16.h>

#define B_   4
#define S_   8192
#define D_   512
#define DFF_ 2048
#define K_TOP 1024

typedef unsigned short u16;
typedef __attribute__((ext_vector_type(8))) short bf16x8;
typedef __attribute__((ext_vector_type(4))) float floatx4;

// monotonic float -> uint key (order-preserving)
__device__ __forceinline__ unsigned f2key(float f){
    unsigned u = __float_as_uint(f);
    return (u & 0x80000000u) ? ~u : (u | 0x80000000u);
}
// fp32 -> bf16 round-to-nearest-even
__device__ __forceinline__ u16 f2b(float f){
    unsigned u = __float_as_uint(f);
    u = (u + 0x7FFFu + ((u >> 16) & 1u)) >> 16;
    return (u16)u;
}
// fast tanh-gelu via v_exp_f32
__device__ __forceinline__ float gelu_fast(float v){
    float u = 1.5957691216f * v + 0.0713548162726f * v * v * v;
    float e = __expf(u);
    return v - v / (e + 1.0f);
}
// async global->LDS, 16B per lane (wave-uniform base + lane*16)
__device__ __forceinline__ void gl_lds16(const void* gptr, void* lptr){
    auto g = (const __attribute__((address_space(1))) unsigned int*)((uintptr_t)gptr);
    auto l = (__attribute__((address_space(3))) unsigned int*)((uintptr_t)lptr);
    __builtin_amdgcn_global_load_lds(g, l, 16, 0, 0);
}

// GEMM operand tiles: [tile][kstep128][128 rows][16 chunks of 16B] bf16,
// chunk c of row r at global slot (c ^ (r&15)). BK=64 staging fetches one
// K-half's 8 chunks with pre-swizzled global addresses; LDS dest is linear.

// ---------------- kernel 1: prep (router + copy-all + ghist + weight conv) -
// blocks [0,128): weight conversion. blocks [128,640): router + x->out copy.
__global__ __launch_bounds__(256) void prep_kernel(
    const float* __restrict__ W1, const float* __restrict__ W2,
    u16* __restrict__ W1t, u16* __restrict__ W2t,
    const float4* __restrict__ x, float4* __restrict__ out,
    const float4* __restrict__ Wr4, const float* __restrict__ br,
    float* __restrict__ w_all, unsigned* __restrict__ ghist)
{
    __shared__ __align__(16) unsigned char shmem[128 * 132 * 2]; // 33 KB union
    const int tid = threadIdx.x;
    const int bx = blockIdx.x;
    if (bx < 128){
        const float* src; u16* dst; int R, C, ct, ks;
        if (bx < 64){ src = W1; dst = W1t; R = D_;   C = DFF_; ct = bx & 15;        ks = bx >> 4; }
        else        { src = W2; dst = W2t; R = DFF_; C = D_;   ct = (bx - 64) & 3;  ks = (bx - 64) >> 2; }
        u16 (*tile)[132] = (u16(*)[132])shmem;
        #pragma unroll
        for (int it = 0; it < 64; it++){
            int lin = it * 256 + tid;
            int kk = lin >> 7, nn = lin & 127;
            tile[kk][nn] = f2b(src[(size_t)(ks * 128 + kk) * C + ct * 128 + nn]);
        }
        __syncthreads();
        u16* base = dst + (size_t)(ct * (R / 128) + ks) * 16384;
        const int r = tid >> 1, h = tid & 1;
        #pragma unroll
        for (int c = 0; c < 8; c++){
            int cl = h * 8 + c;
            bf16x8 bv;
            #pragma unroll
            for (int e = 0; e < 8; e++) bv[e] = (short)tile[cl * 8 + e][r];
            *(bf16x8*)&base[r * 128 + ((cl ^ (r & 15)) << 3)] = bv;
        }
    } else {
        unsigned* hist = (unsigned*)shmem;
        if (tid < 256) hist[tid] = 0u;
        __syncthreads();
        const int wb = bx - 128;                  // 0..511, 128 blocks/batch
        const int wv = tid >> 6, lane = tid & 63;
        const int t0 = wb * 64 + wv * 16;
        const float brv = br[0];
        const float4 wr0 = Wr4[lane], wr1 = Wr4[lane + 64];
        #pragma unroll
        for (int g = 0; g < 4; g++){
            float a[4];
            #pragma unroll
            for (int tt = 0; tt < 4; tt++){
                const int t = t0 + g * 4 + tt;
                const float4* xt = x + (size_t)t * 128;
                float4* ot = out + (size_t)t * 128;
                float4 v0 = xt[lane], v1 = xt[lane + 64];
                ot[lane] = v0; ot[lane + 64] = v1;    // copy-all x->out
                a[tt] = v0.x*wr0.x + v0.y*wr0.y + v0.z*wr0.z + v0.w*wr0.w
                      + v1.x*wr1.x + v1.y*wr1.y + v1.z*wr1.z + v1.w*wr1.w;
            }
            #pragma unroll
            for (int off = 32; off > 0; off >>= 1){
                #pragma unroll
                for (int tt = 0; tt < 4; tt++) a[tt] += __shfl_down(a[tt], off, 64);
            }
            if (lane == 0){
                #pragma unroll
                for (int tt = 0; tt < 4; tt++){
                    float wt = a[tt] + brv;
                    w_all[t0 + g * 4 + tt] = wt;
                    atomicAdd(&hist[f2key(wt) >> 24], 1u);
                }
            }
        }
        __syncthreads();
        if (tid < 256) ghist[wb * 256 + tid] = hist[tid];   // non-atomic row
    }
}

// ------- kernel 2: exact k-th largest per batch, wave0-scan radix ----------
__global__ __launch_bounds__(1024) void kth_compact_kernel(
    const float4* __restrict__ w_all4, const unsigned* __restrict__ ghist,
    int* __restrict__ counts, int* __restrict__ idx)
{
    __shared__ unsigned keys[S_];
    __shared__ unsigned hist[4][256];
    __shared__ unsigned sprefix;
    __shared__ int sremk;
    __shared__ int lbase;
    const int b = blockIdx.x, tid = threadIdx.x;
    const int wv = tid >> 6, lane = tid & 63;
    const float4* row4 = w_all4 + (size_t)b * (S_ / 4);

    #pragma unroll
    for (int i = 0; i < 2; i++){
        int j = tid + i * 1024;
        float4 v = row4[j];
        keys[4*j+0] = f2key(v.x); keys[4*j+1] = f2key(v.y);
        keys[4*j+2] = f2key(v.z); keys[4*j+3] = f2key(v.w);
    }
    // coarse top-byte hist: 4 row-groups of 32 prep-rows each -> hist[q][bin]
    {
        const int bin = tid & 255, q = tid >> 8;
        unsigned s = 0;
        const unsigned* gh = ghist + (size_t)(b * 128 + q * 32) * 256 + bin;
        #pragma unroll 8
        for (int j = 0; j < 32; j++) s += gh[j * 256];
        hist[q][bin] = s;
    }
    if (tid == 0){ sprefix = 0u; sremk = K_TOP; lbase = 0; }
    __syncthreads();

    for (int pass = 3; pass >= 0; pass--){
        const int shift = pass * 8;
        if (pass < 3){
            ((unsigned*)hist)[tid] = 0u;
            __syncthreads();
            const unsigned mask_hi = 0xFFFFFFFFu << (shift + 8);
            const unsigned pfx = sprefix;
            #pragma unroll
            for (int i = 0; i < 8; i++){
                unsigned key = keys[tid + i * 1024];
                if ((key & mask_hi) == pfx)
                    atomicAdd(&hist[wv & 3][(key >> shift) & 255u], 1u);
            }
            __syncthreads();
        }
        if (wv == 0){
            const unsigned remk = (unsigned)sremk;
            const unsigned pfx = sprefix;
            unsigned c[4];
            #pragma unroll
            for (int q = 0; q < 4; q++)
                c[q] = hist[0][4*lane+q] + hist[1][4*lane+q]
                     + hist[2][4*lane+q] + hist[3][4*lane+q];
            unsigned t = c[0] + c[1] + c[2] + c[3];
            unsigned ss = t;
            #pragma unroll
            for (int off = 1; off < 64; off <<= 1){
                unsigned o = __shfl_down(ss, off, 64);
                ss += (lane + off < 64) ? o : 0u;
            }
            const unsigned sgt = ss - t;
            unsigned suf[4];
            suf[3] = c[3] + sgt; suf[2] = c[2] + suf[3];
            suf[1] = c[1] + suf[2]; suf[0] = c[0] + suf[1];
            #pragma unroll
            for (int q = 0; q < 4; q++){
                unsigned nx = suf[q] - c[q];
                if (suf[q] >= remk && nx < remk){
                    sprefix = pfx | ((unsigned)(4 * lane + q) << shift);
                    sremk = (int)(remk - nx);
                }
            }
        }
        __syncthreads();
    }

    const unsigned thr = sprefix;
    #pragma unroll
    for (int i = 0; i < 8; i++){
        int li = tid + i * 1024;
        bool sel = keys[li] > thr;
        unsigned long long m = __ballot(sel);
        int wtot = (int)__popcll(m);
        if (wtot){
            int woff = 0;
            if (lane == 0) woff = atomicAdd(&lbase, wtot);
            woff = __shfl(woff, 0, 64);
            if (sel){
                int pos = woff + (int)__popcll(m & ((1ull << lane) - 1ull));
                idx[b * 1024 + pos] = b * S_ + li;
            }
        }
    }
    __syncthreads();
    if (tid == 0) counts[b] = lbase;
}

// --- kernel 3: gather selected x rows -> bf16 tiled+swizzled ---------------
// XbT tiles [32 mt][4 ks][128 r][128 k]; grid (32, 4). Pays the scatter ONCE.
__global__ __launch_bounds__(256) void gather_kernel(
    const float* __restrict__ x, const int* __restrict__ idx,
    const int* __restrict__ counts, u16* __restrict__ XbT)
{
    const int mt = blockIdx.x, s = blockIdx.y;
    const int cl = threadIdx.x & 15, r16 = threadIdx.x >> 4;
    u16* base = XbT + (size_t)(mt * 4 + s) * 16384;
    #pragma unroll
    for (int it = 0; it < 8; it++){
        int r = r16 + it * 16;
        int mg = mt * 128 + r;
        if ((mg & 1023) < counts[mg >> 10]){
            const float* xp = x + (size_t)idx[mg] * D_ + s * 128 + cl * 8;
            float4 v0 = *(const float4*)xp;
            float4 v1 = *(const float4*)(xp + 4);
            bf16x8 bv;
            bv[0]=(short)f2b(v0.x); bv[1]=(short)f2b(v0.y);
            bv[2]=(short)f2b(v0.z); bv[3]=(short)f2b(v0.w);
            bv[4]=(short)f2b(v1.x); bv[5]=(short)f2b(v1.y);
            bv[6]=(short)f2b(v1.z); bv[7]=(short)f2b(v1.w);
            *(bf16x8*)&base[r * 128 + ((cl ^ (r & 15)) << 3)] = bv;
        }
    }
}

// --- kernel 4: GEMM1 Ht = gelu(Xsel @ W1 + b1), 128x128, BK=64 dbuf --------
// A from XbT via global_load_lds (coalesced). LDS 64 KB -> 2 blk/CU.
// grid 512, XCD-grouped mBlk so each XCD's L2 holds 4 A-panels.
__global__ __launch_bounds__(256) void ffn1_kernel(
    const u16* __restrict__ XbT, const u16* __restrict__ W1t,
    const int* __restrict__ counts, const float* __restrict__ bias1,
    u16* __restrict__ Ht)
{
    __shared__ __align__(16) u16 smem[32768];     // A:2x16KB | B:2x16KB = 64 KB
    const int tid = threadIdx.x, bx = blockIdx.x;
    const int mBlk = (bx & 7) * 4 + ((bx >> 3) & 3);   // XCD keeps 4 mBlks
    const int nBlk = bx >> 5;
    const int lane = tid & 63, w = tid >> 6;
    const int wr = (w >> 1) * 64, wc = (w & 1) * 64;
    const int fr = lane & 15, quad = lane >> 4;

    const char* Abase = (const char*)(XbT + (size_t)mBlk * 4 * 16384);
    const char* Bbase = (const char*)(W1t + (size_t)nBlk * 4 * 16384);
    char* Al0 = (char*)smem + tid * 16;
    char* Bl0 = (char*)(smem + 16384) + tid * 16;
    const int rr0 = tid >> 3, pp = tid & 7;

    auto stage = [&](const char* gbase, char* lb, int hs){
        const char* s0 = gbase + (size_t)(hs >> 1) * 32768;
        const int h = hs & 1;
        #pragma unroll
        for (int i = 0; i < 4; i++){
            int r = rr0 + i * 32;
            int pg = pp | (((h ^ (r >> 3)) & 1) << 3);
            gl_lds16(s0 + r * 256 + pg * 16, lb + i * 4096);
        }
    };

    stage(Abase, Al0, 0);
    stage(Bbase, Bl0, 0);

    floatx4 acc[4][4] = {};
    for (int hs = 0; hs < 8; hs++){
        __builtin_amdgcn_s_barrier();            // WAR: prev-iter reads done
        if (hs + 1 < 8){
            stage(Abase, Al0 + ((hs + 1) & 1) * 16384, hs + 1);
            stage(Bbase, Bl0 + ((hs + 1) & 1) * 16384, hs + 1);
            asm volatile("s_waitcnt vmcnt(8)" ::: "memory");
        } else {
            asm volatile("s_waitcnt vmcnt(0)" ::: "memory");
        }
        __builtin_amdgcn_sched_barrier(0);
        __builtin_amdgcn_s_barrier();            // all waves' stage(hs) landed
        const u16* Ab = smem + (hs & 1) * 8192;
        const u16* Bb = smem + 16384 + (hs & 1) * 8192;
        __builtin_amdgcn_s_setprio(1);
        #pragma unroll
        for (int ks2 = 0; ks2 < 2; ks2++){
            bf16x8 af[4], bf[4];
            #pragma unroll
            for (int i = 0; i < 4; i++){
                int r = wr + i * 16 + fr;
                af[i] = *(const bf16x8*)&Ab[r * 64 + (((ks2 * 4 + quad) ^ (r & 7)) << 3)];
            }
            #pragma unroll
            for (int j = 0; j < 4; j++){
                int r = wc + j * 16 + fr;
                bf[j] = *(const bf16x8*)&Bb[r * 64 + (((ks2 * 4 + quad) ^ (r & 7)) << 3)];
            }
            #pragma unroll
            for (int i = 0; i < 4; i++)
                #pragma unroll
                for (int j = 0; j < 4; j++)
                    acc[i][j] = __builtin_amdgcn_mfma_f32_16x16x32_bf16(af[i], bf[j], acc[i][j], 0, 0, 0);
        }
        __builtin_amdgcn_s_setprio(0);
    }

    float bj[4];
    #pragma unroll
    for (int j = 0; j < 4; j++) bj[j] = bias1[nBlk * 128 + wc + j * 16 + fr];

    __syncthreads();
    u16* Cs = smem;                  // 32KB: [128 r][128 c] swizzled
    #pragma unroll
    for (int i = 0; i < 4; i++){
        #pragma unroll
        for (int rg = 0; rg < 4; rg++){
            int r = wr + i * 16 + quad * 4 + rg;
            #pragma unroll
            for (int j = 0; j < 4; j++){
                int col = wc + j * 16 + fr;
                float v = gelu_fast(acc[i][j][rg] + bj[j]);
                Cs[r * 128 + ((((col >> 3) ^ (r & 15)) << 3) | (col & 7))] = f2b(v);
            }
        }
    }
    __syncthreads();
    const int r = tid >> 1, h = tid & 1;
    int mg = mBlk * 128 + r;
    if ((mg & 1023) < counts[mg >> 10]){
        u16* dstp = Ht + (((size_t)(mBlk * 2 + (r >> 6)) * 16 + nBlk) * 64 + (r & 63)) * 128;
        #pragma unroll
        for (int p = 0; p < 8; p++){
            int pc = h * 8 + p;
            *(bf16x8*)&dstp[pc << 3] = *(const bf16x8*)&Cs[r * 128 + (pc << 3)];
        }
    }
}

// --- kernel 5: GEMM2 out = (H @ W2 + b2) * w, 64x64 tile, BK=64 dbuf -------
// Retiled: grid 512 (2 blk/CU), LDS 32 KB (A 2x8K + B 2x8K).
// mBlk grouped per XCD: A panels 2 MB L2-resident; B (4 MB W2t) ~L2-fits.
__global__ __launch_bounds__(256) void ffn2_kernel(
    const u16* __restrict__ Ht, const u16* __restrict__ W2t,
    const int* __restrict__ counts, const int* __restrict__ idx,
    const float* __restrict__ w_all, const float* __restrict__ bias2,
    float* __restrict__ out)
{
    __shared__ __align__(16) u16 smem[16384];     // 32 KB
    const int tid = threadIdx.x, bx = blockIdx.x;
    const int xcd = bx & 7, inner = bx >> 3;
    const int mBlk = xcd * 8 + (inner & 7);            // [0,64)
    const int nBlk2 = inner >> 3;                      // [0,8): 64-col slice
    const int ct = nBlk2 >> 1, roff = (nBlk2 & 1) * 64;
    const int lane = tid & 63, w = tid >> 6;
    const int wr = (w >> 1) * 32, wc = (w & 1) * 32;
    const int fr = lane & 15, quad = lane >> 4;

    const char* Abase = (const char*)(Ht + (size_t)mBlk * 16 * 8192);
    const char* Bbase = (const char*)(W2t + (size_t)ct * 16 * 16384);
    char* Al0 = (char*)smem + tid * 16;                // A dbuf bytes [0,16K)
    char* Bl0 = (char*)smem + 16384 + tid * 16;        // B dbuf bytes [16K,32K)
    const int rr0 = tid >> 3, pp = tid & 7;

    auto stage = [&](int buf, int hs){
        const int h = hs & 1;
        {   // A: [64 m][64 k] = 8KB, 2 loads
            const char* s0 = Abase + (size_t)(hs >> 1) * 16384;
            char* l = Al0 + buf * 8192;
            #pragma unroll
            for (int i = 0; i < 2; i++){
                int r = rr0 + i * 32;
                int pg = pp | (((h ^ (r >> 3)) & 1) << 3);
                gl_lds16(s0 + r * 256 + pg * 16, l + i * 4096);
            }
        }
        {   // B: rows [roff, roff+64) of the [128][128k] tile = 8KB, 2 loads
            const char* s0 = Bbase + (size_t)(hs >> 1) * 32768;
            char* l = Bl0 + buf * 8192;
            #pragma unroll
            for (int i = 0; i < 2; i++){
                int rl = rr0 + i * 32;                 // local row [0,64)
                int rg = roff + rl;                    // global tile row
                int pg = pp | (((h ^ (rl >> 3)) & 1) << 3);  // parity inv. to +64
                gl_lds16(s0 + rg * 256 + pg * 16, l + i * 4096);
            }
        }
    };

    stage(0, 0);
    floatx4 acc[2][2] = {};
    for (int hs = 0; hs < 32; hs++){
        __builtin_amdgcn_s_barrier();            // WAR: prev-iter reads done
        if (hs + 1 < 32){
            stage((hs + 1) & 1, hs + 1);
            asm volatile("s_waitcnt vmcnt(4)" ::: "memory");
        } else {
            asm volatile("s_waitcnt vmcnt(0)" ::: "memory");
        }
        __builtin_amdgcn_sched_barrier(0);
        __builtin_amdgcn_s_barrier();            // all waves' stage(hs) landed
        const u16* Ab = (const u16*)((const char*)smem + (hs & 1) * 8192);
        const u16* Bb = (const u16*)((const char*)smem + 16384 + (hs & 1) * 8192);
        __builtin_amdgcn_s_setprio(1);
        #pragma unroll
        for (int ks2 = 0; ks2 < 2; ks2++){
            bf16x8 af[2], bf[2];
            #pragma unroll
            for (int i = 0; i < 2; i++){
                int r = wr + i * 16 + fr;
                af[i] = *(const bf16x8*)&Ab[r * 64 + (((ks2 * 4 + quad) ^ (r & 7)) << 3)];
            }
            #pragma unroll
            for (int j = 0; j < 2; j++){
                int r = wc + j * 16 + fr;
                bf[j] = *(const bf16x8*)&Bb[r * 64 + (((ks2 * 4 + quad) ^ (r & 7)) << 3)];
            }
            #pragma unroll
            for (int i = 0; i < 2; i++)
                #pragma unroll
                for (int j = 0; j < 2; j++)
                    acc[i][j] = __builtin_amdgcn_mfma_f32_16x16x32_bf16(af[i], bf[j], acc[i][j], 0, 0, 0);
        }
        __builtin_amdgcn_s_setprio(0);
    }

    float bj[2];
    #pragma unroll
    for (int j = 0; j < 2; j++) bj[j] = bias2[nBlk2 * 64 + wc + j * 16 + fr];

    __syncthreads();
    float* Cs = (float*)smem;        // 16KB: [64 r][64 c]
    #pragma unroll
    for (int i = 0; i < 2; i++){
        #pragma unroll
        for (int rg = 0; rg < 4; rg++){
            int r = wr + i * 16 + quad * 4 + rg;
            #pragma unroll
            for (int j = 0; j < 2; j++)
                Cs[r * 64 + wc + j * 16 + fr] = acc[i][j][rg] + bj[j];
        }
    }
    __syncthreads();
    const int r = tid >> 2, q = tid & 3;
    int mg = mBlk * 64 + r;
    if ((mg & 1023) < counts[mg >> 10]){
        int token = idx[mg];
        float wt = w_all[token];
        float* op = out + (size_t)token * D_ + nBlk2 * 64 + q * 16;
        const float4* cp = (const float4*)&Cs[r * 64 + q * 16];
        #pragma unroll
        for (int p = 0; p < 4; p++){
            float4 vv = cp[p];
            vv.x *= wt; vv.y *= wt; vv.z *= wt; vv.w *= wt;
            ((float4*)op)[p] = vv;
        }
    }
}

extern "C" void kernel_launch(void* const* d_in, const int* in_sizes, int n_in,
                              void* d_out, int out_size, void* d_ws, size_t ws_size,
                              hipStream_t stream)
{
    const float* x  = (const float*)d_in[0];
    const float* Wr = (const float*)d_in[2];
    const float* br = (const float*)d_in[3];
    const float* W1 = (const float*)d_in[4];
    const float* b1 = (const float*)d_in[5];
    const float* W2 = (const float*)d_in[6];
    const float* b2 = (const float*)d_in[7];
    float* out = (float*)d_out;
    char* ws = (char*)d_ws;

    // workspace layout (bytes)
    float*    w_all  = (float*)   (ws + 0);         // 128 KB
    int*      counts = (int*)     (ws + 131072);    // 16 B
    int*      idx    = (int*)     (ws + 131136);    // 16 KB [4][1024]
    unsigned* ghist  = (unsigned*)(ws + 163840);    // 512 KB [512][256]
    u16*      XbT    = (u16*)     (ws + 720896);    // 4 MB  [32][4][128][128]
    u16*      W1t    = (u16*)     (ws + 4915200);   // 2 MB  [16][4][128][128]
    u16*      W2t    = (u16*)     (ws + 7012352);   // 2 MB  [4][16][128][128]
    u16*      Ht     = (u16*)     (ws + 9109504);   // 16 MB [64][16][64][128]

    prep_kernel<<<640, 256, 0, stream>>>(
        W1, W2, W1t, W2t, (const float4*)x, (float4*)out,
        (const float4*)Wr, br, w_all, ghist);
    kth_compact_kernel<<<B_, 1024, 0, stream>>>(
        (const float4*)w_all, ghist, counts, idx);
    gather_kernel<<<dim3(32, 4), 256, 0, stream>>>(x, idx, counts, XbT);
    ffn1_kernel<<<512, 256, 0, stream>>>(
        XbT, W1t, counts, b1, Ht);
    ffn2_kernel<<<512, 256, 0, stream>>>(
        Ht, W2t, counts, idx, w_all, b2, out);
}